// Round 11
// baseline (1592.595 us; speedup 1.0000x reference)
//
#include <hip/hip_runtime.h>
#include <math.h>

#define LSEQ 256
#define HID 256
#define H2 512
#define H3 768
#define H8 2048

typedef __attribute__((ext_vector_type(8))) short short8;
typedef __attribute__((ext_vector_type(4))) float floatx4;

__device__ __forceinline__ unsigned short f2bf(float f) {
    unsigned int u = __float_as_uint(f);
    u = (u + 0x7FFFu + ((u >> 16) & 1u)) >> 16;
    return (unsigned short)u;
}
__device__ __forceinline__ float bf2f(unsigned short h) {
    return __uint_as_float(((unsigned int)h) << 16);
}
__device__ __forceinline__ float fsig(float x) {
    return __builtin_amdgcn_rcpf(1.f + __expf(-x));
}
__device__ __forceinline__ float ftanh(float x) {
    return __builtin_fmaf(2.f, __builtin_amdgcn_rcpf(1.f + __expf(-2.f * x)), -1.f);
}
// async global->LDS 16B per lane: LDS dest = base + lane*16 (wave-uniform base)
__device__ __forceinline__ void gload_lds16(const void* g, void* l) {
    __builtin_amdgcn_global_load_lds(
        (const __attribute__((address_space(1))) unsigned int*)g,
        (__attribute__((address_space(3))) unsigned int*)l, 16, 0, 0);
}

// ---------------- embed (bf16 out) ----------------
__global__ void embed_kernel(const int* __restrict__ question,
                             const int* __restrict__ article,
                             const float* __restrict__ emb,
                             unsigned short* __restrict__ xemb) {
    int gid = blockIdx.x * 256 + threadIdx.x;   // 128*256*256
    int d = gid & 255;
    int rl = gid >> 8;
    int l = rl & 255;
    int stream = rl >> 8;
    int id;
    if (stream < 64) {
        int b = stream >> 3, o = (stream & 7) >> 1;
        id = question[(b * 4 + o) * 256 + l];
    } else {
        id = article[(stream - 64) * 256 + l];
    }
    xemb[(size_t)gid] = f2bf(emb[(size_t)id * 256 + d]);
}

// all 4 weight tensors in one launch (3 x 49152 + 393216 = 540672 uint4-units)
__global__ void pack_weights(const float* __restrict__ g1whh, const float* __restrict__ g1wih,
                             const float* __restrict__ g2whh, const float* __restrict__ g2wih,
                             unsigned short* __restrict__ wpk1, unsigned short* __restrict__ wih1,
                             unsigned short* __restrict__ wpk2, unsigned short* __restrict__ wih2) {
    int i = blockIdx.x * 256 + threadIdx.x;
    const float* src; unsigned short* dst; int j;
    if (i < 49152)       { src = g1whh; dst = wpk1; j = i; }
    else if (i < 98304)  { src = g1wih; dst = wih1; j = i - 49152; }
    else if (i < 147456) { src = g2whh; dst = wpk2; j = i - 98304; }
    else if (i < 540672) { src = g2wih; dst = wih2; j = i - 147456; }
    else return;
    float4 a = ((const float4*)src)[2 * j];
    float4 b = ((const float4*)src)[2 * j + 1];
    uint4 o;
    o.x = (unsigned int)f2bf(a.x) | ((unsigned int)f2bf(a.y) << 16);
    o.y = (unsigned int)f2bf(a.z) | ((unsigned int)f2bf(a.w) << 16);
    o.z = (unsigned int)f2bf(b.x) | ((unsigned int)f2bf(b.y) << 16);
    o.w = (unsigned int)f2bf(b.z) | ((unsigned int)f2bf(b.w) << 16);
    ((uint4*)dst)[j] = o;
}

// ---------------- MFMA GEMM, both GRU dirs fused; global_load_lds staging ----------------
__global__ __launch_bounds__(256)
void gemm_2dir(const unsigned short* __restrict__ A, const unsigned short* __restrict__ B,
               const float* __restrict__ bias, unsigned short* __restrict__ C0,
               unsigned short* __restrict__ C1, int mbase, int K) {
    __shared__ __align__(16) unsigned short At[128][32];
    __shared__ __align__(16) unsigned short Bt[128][32];
    int tid = threadIdx.x;
    int m0 = blockIdx.x * 128, n0 = blockIdx.y * 128;
    int l = tid & 63, w = tid >> 6;          // 4 waves
    int wm = (w & 1) * 64, wn = (w >> 1) * 64;
    int lr = l & 15, kq = l >> 4;
    int subrow = l >> 2;
    int swc = (l & 3) ^ (subrow & 3);
    const unsigned short* gA0 = A + (size_t)(m0 + w * 32 + subrow) * K + swc * 8;
    const unsigned short* gA1 = A + (size_t)(m0 + w * 32 + 16 + subrow) * K + swc * 8;
    const unsigned short* gB0 = B + (size_t)(n0 + w * 32 + subrow) * K + swc * 8;
    const unsigned short* gB1 = B + (size_t)(n0 + w * 32 + 16 + subrow) * K + swc * 8;
    unsigned short* lA0 = &At[w * 32][0];
    unsigned short* lA1 = &At[w * 32 + 16][0];
    unsigned short* lB0 = &Bt[w * 32][0];
    unsigned short* lB1 = &Bt[w * 32 + 16][0];
    int rchunk = (kq ^ (lr & 3)) * 8;
    floatx4 acc[4][4];
#pragma unroll
    for (int i = 0; i < 4; i++)
#pragma unroll
        for (int j = 0; j < 4; j++) acc[i][j] = (floatx4){0.f, 0.f, 0.f, 0.f};
    for (int k0 = 0; k0 < K; k0 += 32) {
        __syncthreads();
        gload_lds16(gA0 + k0, lA0);
        gload_lds16(gA1 + k0, lA1);
        gload_lds16(gB0 + k0, lB0);
        gload_lds16(gB1 + k0, lB1);
        __syncthreads();
        short8 af[4], bf[4];
#pragma unroll
        for (int i = 0; i < 4; i++) {
            af[i] = *(const short8*)&At[wm + i * 16 + lr][rchunk];
            bf[i] = *(const short8*)&Bt[wn + i * 16 + lr][rchunk];
        }
#pragma unroll
        for (int i = 0; i < 4; i++)
#pragma unroll
            for (int j = 0; j < 4; j++)
                acc[i][j] = __builtin_amdgcn_mfma_f32_16x16x32_bf16(af[i], bf[j], acc[i][j], 0, 0, 0);
    }
    int quad = l >> 4;
#pragma unroll
    for (int i = 0; i < 4; i++) {
#pragma unroll
        for (int j = 0; j < 4; j++) {
            int n = n0 + wn + j * 16 + lr;
            float bs = bias[n];
            unsigned short* dst = (n < 768) ? C0 : C1;
            int nn = (n < 768) ? n : n - 768;
#pragma unroll
            for (int r = 0; r < 4; r++) {
                int m = mbase + m0 + wm + i * 16 + quad * 4 + r;
                dst[(size_t)m * 768 + nn] = f2bf(acc[i][j][r] + bs);
            }
        }
    }
}

// ---------------- GRU scan: 1 stream/block, whh in VGPRs, in-wave gates ----------------
// R11: accumulator 2-way split — 12 independent 4-deep MFMA chains instead of
// 6×8-deep, halving the dependent-latency critical path.
__global__ __launch_bounds__(512, 2)
void gru_scan_rreg(const unsigned short* __restrict__ gi_f,
                   const unsigned short* __restrict__ gi_b,
                   const unsigned short* __restrict__ whh_bf,
                   const float* __restrict__ bhh,
                   float* __restrict__ out) {
    int blk = blockIdx.x;
    int d = blk & 1, s = blk >> 1;
    const unsigned short* gi_blk = (d ? gi_b : gi_f) + (size_t)s * LSEQ * H3;
    const unsigned short* wb = whh_bf + (size_t)d * H3 * HID;

    __shared__ __align__(16) unsigned short h_pack[2][256];  // double-buffered h (bf16)

    int tid = threadIdx.x;
    int lane = tid & 63, wave = tid >> 6;
    int lr = lane & 15, kq = lane >> 4;

    short8 bq[6][8];
#pragma unroll
    for (int nt = 0; nt < 6; nt++) {
        int row = (nt >> 1) * 256 + wave * 32 + (nt & 1) * 16 + lr;
        const unsigned short* wp = wb + (size_t)row * HID + kq * 8;
#pragma unroll
        for (int kt = 0; kt < 8; kt++)
            bq[nt][kt] = *(const short8*)(wp + kt * 32);
    }

    int hh0 = wave * 32 + lr, hh1 = hh0 + 16;
    float br0 = bhh[d * H3 + hh0],       br1 = bhh[d * H3 + hh1];
    float bz0 = bhh[d * H3 + 256 + hh0], bz1 = bhh[d * H3 + 256 + hh1];
    float bn0 = bhh[d * H3 + 512 + hh0], bn1 = bhh[d * H3 + 512 + hh1];

    int t0 = d ? (LSEQ - 1) : 0;
    int tstep = d ? -1 : 1;

    if (tid < 128) ((unsigned int*)h_pack[0])[tid] = 0;
    float hold0 = 0.f, hold1 = 0.f;

    unsigned short gr0, gz0, gn0, gr1, gz1, gn1;
    {
        const unsigned short* gp = gi_blk + (size_t)t0 * H3;
        gr0 = gp[hh0]; gz0 = gp[256 + hh0]; gn0 = gp[512 + hh0];
        gr1 = gp[hh1]; gz1 = gp[256 + hh1]; gn1 = gp[512 + hh1];
    }
    __syncthreads();

    int cur = 0, t = t0;
    for (int step = 0; step < LSEQ; ++step) {
        unsigned short nr0 = 0, nz0 = 0, nn0 = 0, nr1 = 0, nz1 = 0, nn1 = 0;
        if (step + 1 < LSEQ) {
            const unsigned short* gp = gi_blk + (size_t)(t + tstep) * H3;
            nr0 = gp[hh0]; nz0 = gp[256 + hh0]; nn0 = gp[512 + hh0];
            nr1 = gp[hh1]; nz1 = gp[256 + hh1]; nn1 = gp[512 + hh1];
        }
        floatx4 accA[6], accB[6];
#pragma unroll
        for (int nt = 0; nt < 6; nt++) {
            accA[nt] = (floatx4){0.f, 0.f, 0.f, 0.f};
            accB[nt] = (floatx4){0.f, 0.f, 0.f, 0.f};
        }
#pragma unroll
        for (int kt = 0; kt < 4; kt++) {
            short8 avA = *(const short8*)&h_pack[cur][kt * 32 + kq * 8];        // broadcast
            short8 avB = *(const short8*)&h_pack[cur][(kt + 4) * 32 + kq * 8];  // broadcast
#pragma unroll
            for (int nt = 0; nt < 6; nt++) {
                accA[nt] = __builtin_amdgcn_mfma_f32_16x16x32_bf16(avA, bq[nt][kt], accA[nt], 0, 0, 0);
                accB[nt] = __builtin_amdgcn_mfma_f32_16x16x32_bf16(avB, bq[nt][kt + 4], accB[nt], 0, 0, 0);
            }
        }
        float p0 = accA[0][0] + accB[0][0];
        float p1 = accA[1][0] + accB[1][0];
        float p2 = accA[2][0] + accB[2][0];
        float p3 = accA[3][0] + accB[3][0];
        float p4 = accA[4][0] + accB[4][0];
        float p5 = accA[5][0] + accB[5][0];
        float rg0 = fsig(bf2f(gr0) + p0 + br0);
        float rg1 = fsig(bf2f(gr1) + p1 + br1);
        float zg0 = fsig(bf2f(gz0) + p2 + bz0);
        float zg1 = fsig(bf2f(gz1) + p3 + bz1);
        float ng0 = ftanh(bf2f(gn0) + rg0 * (p4 + bn0));
        float ng1 = ftanh(bf2f(gn1) + rg1 * (p5 + bn1));
        float h0 = (1.f - zg0) * ng0 + zg0 * hold0;
        float h1 = (1.f - zg1) * ng1 + zg1 * hold1;
        hold0 = h0; hold1 = h1;
        int nxt = cur ^ 1;
        if (kq == 0) {
            h_pack[nxt][hh0] = f2bf(h0);
            h_pack[nxt][hh1] = f2bf(h1);
            float* op = out + ((size_t)s * LSEQ + t) * H2 + d * HID;
            op[hh0] = h0;
            op[hh1] = h1;
        }
        gr0 = nr0; gz0 = nz0; gn0 = nn0;
        gr1 = nr1; gz1 = nz1; gn1 = nn1;
        __syncthreads();
        cur = nxt; t += tstep;
    }
}

// ---------------- smat via MFMA split-bf16 (trunc-split), FUSED cw/qw dots ----------------
// S[m][n] = sum_k (c[m][k]*w2[k]) * q[n][k] + cw[m] + qw[n] + bsum
// trunc-split: hi = top-16 bits (1 op), lo = rne-bf16(x - hi); hi+lo ~ x to 2^-17.
__global__ __launch_bounds__(256)
void smat_mfma(const float* __restrict__ c, const float* __restrict__ q,
               const float* __restrict__ w1, const float* __restrict__ bvec,
               float* __restrict__ smat) {
    __shared__ __align__(16) unsigned short Ah[128][40];
    __shared__ __align__(16) unsigned short Al[128][40];
    __shared__ __align__(16) unsigned short Bh[128][40];
    __shared__ __align__(16) unsigned short Bl[128][40];
    __shared__ float cwl[128];
    __shared__ float qwl[128];
    const float* w2 = w1 + 1024;
    int b = blockIdx.z;
    int m0 = blockIdx.x * 128, n0 = blockIdx.y * 128;
    int tid = threadIdx.x;
    int l = tid & 63, w = tid >> 6;
    int wm = (w & 1) * 64, wn = (w >> 1) * 64;
    int lr = l & 15, koff = (l >> 4) * 8;
    int srow = tid >> 1, scol = (tid & 1) * 16;
    floatx4 acc[4][4];
#pragma unroll
    for (int i = 0; i < 4; i++)
#pragma unroll
        for (int j = 0; j < 4; j++) acc[i][j] = (floatx4){0.f, 0.f, 0.f, 0.f};
    const float* ap0 = c + (size_t)(b * 256 + m0 + srow) * H2 + scol;
    const float* bp0 = q + (size_t)(b * 256 + n0 + srow) * H2 + scol;
    float pcw = 0.f, pqw = 0.f;
    for (int k0 = 0; k0 < H2; k0 += 32) {
        float av[16], bv[16], wv[16], wc[16], wq[16];
        *(float4*)&av[0]  = *(const float4*)(ap0 + k0);
        *(float4*)&av[4]  = *(const float4*)(ap0 + k0 + 4);
        *(float4*)&av[8]  = *(const float4*)(ap0 + k0 + 8);
        *(float4*)&av[12] = *(const float4*)(ap0 + k0 + 12);
        *(float4*)&bv[0]  = *(const float4*)(bp0 + k0);
        *(float4*)&bv[4]  = *(const float4*)(bp0 + k0 + 4);
        *(float4*)&bv[8]  = *(const float4*)(bp0 + k0 + 8);
        *(float4*)&bv[12] = *(const float4*)(bp0 + k0 + 12);
        *(float4*)&wv[0]  = *(const float4*)(w2 + k0 + scol);
        *(float4*)&wv[4]  = *(const float4*)(w2 + k0 + scol + 4);
        *(float4*)&wv[8]  = *(const float4*)(w2 + k0 + scol + 8);
        *(float4*)&wv[12] = *(const float4*)(w2 + k0 + scol + 12);
        *(float4*)&wc[0]  = *(const float4*)(w1 + k0 + scol);
        *(float4*)&wc[4]  = *(const float4*)(w1 + k0 + scol + 4);
        *(float4*)&wc[8]  = *(const float4*)(w1 + k0 + scol + 8);
        *(float4*)&wc[12] = *(const float4*)(w1 + k0 + scol + 12);
        *(float4*)&wq[0]  = *(const float4*)(w1 + 512 + k0 + scol);
        *(float4*)&wq[4]  = *(const float4*)(w1 + 512 + k0 + scol + 4);
        *(float4*)&wq[8]  = *(const float4*)(w1 + 512 + k0 + scol + 8);
        *(float4*)&wq[12] = *(const float4*)(w1 + 512 + k0 + scol + 12);
#pragma unroll
        for (int j = 0; j < 16; j++) { pcw += av[j] * wc[j]; pqw += bv[j] * wq[j]; }
        unsigned int ahw[8], alw[8], bhw[8], blw[8];
#pragma unroll
        for (int j = 0; j < 8; j++) {
            float a0 = av[2 * j] * wv[2 * j], a1 = av[2 * j + 1] * wv[2 * j + 1];
            unsigned int u0 = __float_as_uint(a0), u1 = __float_as_uint(a1);
            ahw[j] = (u0 >> 16) | (u1 & 0xFFFF0000u);
            float r0 = a0 - __uint_as_float(u0 & 0xFFFF0000u);
            float r1 = a1 - __uint_as_float(u1 & 0xFFFF0000u);
            alw[j] = (unsigned int)f2bf(r0) | ((unsigned int)f2bf(r1) << 16);
            unsigned int v0 = __float_as_uint(bv[2 * j]), v1 = __float_as_uint(bv[2 * j + 1]);
            bhw[j] = (v0 >> 16) | (v1 & 0xFFFF0000u);
            float s0 = bv[2 * j]     - __uint_as_float(v0 & 0xFFFF0000u);
            float s1 = bv[2 * j + 1] - __uint_as_float(v1 & 0xFFFF0000u);
            blw[j] = (unsigned int)f2bf(s0) | ((unsigned int)f2bf(s1) << 16);
        }
        __syncthreads();
        *(uint4*)&Ah[srow][scol]     = *(uint4*)&ahw[0];
        *(uint4*)&Ah[srow][scol + 8] = *(uint4*)&ahw[4];
        *(uint4*)&Al[srow][scol]     = *(uint4*)&alw[0];
        *(uint4*)&Al[srow][scol + 8] = *(uint4*)&alw[4];
        *(uint4*)&Bh[srow][scol]     = *(uint4*)&bhw[0];
        *(uint4*)&Bh[srow][scol + 8] = *(uint4*)&bhw[4];
        *(uint4*)&Bl[srow][scol]     = *(uint4*)&blw[0];
        *(uint4*)&Bl[srow][scol + 8] = *(uint4*)&blw[4];
        __syncthreads();
        short8 afh[4], afl[4], bfh[4], bfl[4];
#pragma unroll
        for (int i = 0; i < 4; i++) {
            afh[i] = *(const short8*)&Ah[wm + i * 16 + lr][koff];
            afl[i] = *(const short8*)&Al[wm + i * 16 + lr][koff];
            bfh[i] = *(const short8*)&Bh[wn + i * 16 + lr][koff];
            bfl[i] = *(const short8*)&Bl[wn + i * 16 + lr][koff];
        }
#pragma unroll
        for (int i = 0; i < 4; i++)
#pragma unroll
            for (int j = 0; j < 4; j++) {
                acc[i][j] = __builtin_amdgcn_mfma_f32_16x16x32_bf16(afl[i], bfh[j], acc[i][j], 0, 0, 0);
                acc[i][j] = __builtin_amdgcn_mfma_f32_16x16x32_bf16(afh[i], bfl[j], acc[i][j], 0, 0, 0);
                acc[i][j] = __builtin_amdgcn_mfma_f32_16x16x32_bf16(afh[i], bfh[j], acc[i][j], 0, 0, 0);
            }
    }
    // pair-reduce the cw/qw partial dots (lanes tid, tid^1 share srow)
    pcw += __shfl_xor(pcw, 1);
    pqw += __shfl_xor(pqw, 1);
    if ((tid & 1) == 0) { cwl[srow] = pcw; qwl[srow] = pqw; }
    __syncthreads();
    float bsum = bvec[0] + bvec[1] + bvec[2];
    int quad = l >> 4;
#pragma unroll
    for (int i = 0; i < 4; i++) {
#pragma unroll
        for (int j = 0; j < 4; j++) {
            int n = n0 + wn + j * 16 + lr;
            float qwv = qwl[wn + j * 16 + lr] + bsum;
#pragma unroll
            for (int r = 0; r < 4; r++) {
                int m = m0 + wm + i * 16 + quad * 4 + r;
                smat[((size_t)(b * 256 + m)) * 256 + n] =
                    acc[i][j][r] + cwl[wm + i * 16 + quad * 4 + r] + qwv;
            }
        }
    }
}

__global__ void softmax_kernel(float* __restrict__ smat, float* __restrict__ rowmax) {
    int row = blockIdx.x;
    int lane = threadIdx.x;
    float* p = smat + (size_t)row * LSEQ;
    float v[4];
    float mx = -1e30f;
#pragma unroll
    for (int j = 0; j < 4; j++) { v[j] = p[lane + j * 64]; mx = fmaxf(mx, v[j]); }
    for (int off = 32; off; off >>= 1) mx = fmaxf(mx, __shfl_down(mx, off));
    mx = __shfl(mx, 0);
    float sum = 0.f;
#pragma unroll
    for (int j = 0; j < 4; j++) { v[j] = __expf(v[j] - mx); sum += v[j]; }
    for (int off = 32; off; off >>= 1) sum += __shfl_down(sum, off);
    sum = __shfl(sum, 0);
    float inv = 1.f / sum;
#pragma unroll
    for (int j = 0; j < 4; j++) p[lane + j * 64] = v[j] * inv;
    if (lane == 0) rowmax[row] = mx;
}

__global__ void bb_kernel(const float* __restrict__ rowmax, float* __restrict__ bb) {
    int b = blockIdx.x; int t = threadIdx.x;
    __shared__ float red[256];
    float v = rowmax[b * LSEQ + t];
    red[t] = v; __syncthreads();
    for (int s = 128; s; s >>= 1) { if (t < s) red[t] = fmaxf(red[t], red[t + s]); __syncthreads(); }
    float mx = red[0]; __syncthreads();
    float e = __expf(v - mx);
    red[t] = e; __syncthreads();
    for (int s = 128; s; s >>= 1) { if (t < s) red[t] += red[t + s]; __syncthreads(); }
    bb[b * LSEQ + t] = e / red[0];
}

// q2c: grid (64,4) x 128 thr; 4 independent accumulators break the add chain
__global__ void q2c_kernel(const float* __restrict__ bb, const float* __restrict__ c,
                           float* __restrict__ q2c) {
    int b = blockIdx.x;
    int d = blockIdx.y * 128 + threadIdx.x;
    const float* cb = c + (size_t)b * LSEQ * H2 + d;
    const float* bbp = bb + b * LSEQ;
    float a0 = 0.f, a1 = 0.f, a2 = 0.f, a3 = 0.f;
    for (int i = 0; i < LSEQ; i += 4) {
        a0 += bbp[i]     * cb[(size_t)i * H2];
        a1 += bbp[i + 1] * cb[(size_t)(i + 1) * H2];
        a2 += bbp[i + 2] * cb[(size_t)(i + 2) * H2];
        a3 += bbp[i + 3] * cb[(size_t)(i + 3) * H2];
    }
    q2c[b * H2 + d] = (a0 + a1) + (a2 + a3);
}

// c2q via MFMA split-bf16 (trunc-split) with FUSED fixup03 epilogue; ATT bf16.
__global__ __launch_bounds__(256)
void c2q_fix_mfma(const float* __restrict__ amat, const float* __restrict__ q,
                  const float* __restrict__ c, const float* __restrict__ q2c,
                  unsigned short* __restrict__ att, int add) {
    __shared__ __align__(16) unsigned short Ah[128][40];
    __shared__ __align__(16) unsigned short Al[128][40];
    __shared__ __align__(16) unsigned short Bh[128][40];
    __shared__ __align__(16) unsigned short Bl[128][40];
    int b = blockIdx.z;
    int m0 = blockIdx.x * 128, n0 = blockIdx.y * 128;
    int tid = threadIdx.x;
    int l = tid & 63, w = tid >> 6;
    int wm = (w & 1) * 64, wn = (w >> 1) * 64;
    int lr = l & 15, koff = (l >> 4) * 8;
    int srow = tid >> 1, scol = (tid & 1) * 16;
    int bn = tid & 127, bkh = tid >> 7;           // B-stage: column n0+bn, k-half bkh
    floatx4 acc[4][4];
#pragma unroll
    for (int i = 0; i < 4; i++)
#pragma unroll
        for (int j = 0; j < 4; j++) acc[i][j] = (floatx4){0.f, 0.f, 0.f, 0.f};
    for (int k0 = 0; k0 < LSEQ; k0 += 32) {
        float av[16];
        const float* ap = amat + (size_t)(b * 256 + m0 + srow) * 256 + k0 + scol;
        *(float4*)&av[0]  = *(const float4*)(ap);
        *(float4*)&av[4]  = *(const float4*)(ap + 4);
        *(float4*)&av[8]  = *(const float4*)(ap + 8);
        *(float4*)&av[12] = *(const float4*)(ap + 12);
        float qv[16];
        const float* qp = q + (size_t)(b * 256 + k0 + bkh * 16) * H2 + n0 + bn;
#pragma unroll
        for (int j = 0; j < 16; j++) qv[j] = qp[(size_t)j * H2];
        unsigned int ahw[8], alw[8], bhw[8], blw[8];
#pragma unroll
        for (int j = 0; j < 8; j++) {
            unsigned int u0 = __float_as_uint(av[2 * j]), u1 = __float_as_uint(av[2 * j + 1]);
            ahw[j] = (u0 >> 16) | (u1 & 0xFFFF0000u);
            float r0 = av[2 * j]     - __uint_as_float(u0 & 0xFFFF0000u);
            float r1 = av[2 * j + 1] - __uint_as_float(u1 & 0xFFFF0000u);
            alw[j] = (unsigned int)f2bf(r0) | ((unsigned int)f2bf(r1) << 16);
            unsigned int v0 = __float_as_uint(qv[2 * j]), v1 = __float_as_uint(qv[2 * j + 1]);
            bhw[j] = (v0 >> 16) | (v1 & 0xFFFF0000u);
            float s0 = qv[2 * j]     - __uint_as_float(v0 & 0xFFFF0000u);
            float s1 = qv[2 * j + 1] - __uint_as_float(v1 & 0xFFFF0000u);
            blw[j] = (unsigned int)f2bf(s0) | ((unsigned int)f2bf(s1) << 16);
        }
        __syncthreads();
        *(uint4*)&Ah[srow][scol]         = *(uint4*)&ahw[0];
        *(uint4*)&Ah[srow][scol + 8]     = *(uint4*)&ahw[4];
        *(uint4*)&Al[srow][scol]         = *(uint4*)&alw[0];
        *(uint4*)&Al[srow][scol + 8]     = *(uint4*)&alw[4];
        *(uint4*)&Bh[bn][bkh * 16]       = *(uint4*)&bhw[0];
        *(uint4*)&Bh[bn][bkh * 16 + 8]   = *(uint4*)&bhw[4];
        *(uint4*)&Bl[bn][bkh * 16]       = *(uint4*)&blw[0];
        *(uint4*)&Bl[bn][bkh * 16 + 8]   = *(uint4*)&blw[4];
        __syncthreads();
        short8 afh[4], afl[4], bfh[4], bfl[4];
#pragma unroll
        for (int i = 0; i < 4; i++) {
            afh[i] = *(const short8*)&Ah[wm + i * 16 + lr][koff];
            afl[i] = *(const short8*)&Al[wm + i * 16 + lr][koff];
            bfh[i] = *(const short8*)&Bh[wn + i * 16 + lr][koff];
            bfl[i] = *(const short8*)&Bl[wn + i * 16 + lr][koff];
        }
#pragma unroll
        for (int i = 0; i < 4; i++)
#pragma unroll
            for (int j = 0; j < 4; j++) {
                acc[i][j] = __builtin_amdgcn_mfma_f32_16x16x32_bf16(afl[i], bfh[j], acc[i][j], 0, 0, 0);
                acc[i][j] = __builtin_amdgcn_mfma_f32_16x16x32_bf16(afh[i], bfl[j], acc[i][j], 0, 0, 0);
                acc[i][j] = __builtin_amdgcn_mfma_f32_16x16x32_bf16(afh[i], bfh[j], acc[i][j], 0, 0, 0);
            }
    }
    int quad = l >> 4;
#pragma unroll
    for (int i = 0; i < 4; i++) {
#pragma unroll
        for (int j = 0; j < 4; j++) {
            int n = n0 + wn + j * 16 + lr;
            float q2cv = q2c[b * H2 + n];
#pragma unroll
            for (int r = 0; r < 4; r++) {
                int m = m0 + wm + i * 16 + quad * 4 + r;
                size_t row = (size_t)b * 256 + m;
                float a = acc[i][j][r];
                float cv = c[row * H2 + n];
                float v0 = fmaxf(cv, 0.f);
                float v1 = fmaxf(a, 0.f);
                float v2 = fmaxf(cv * a, 0.f);
                float v3 = fmaxf(cv * q2cv, 0.f);
                unsigned short* p0 = att + row * H8 + n;
                if (add) {
                    p0[0]    = f2bf(bf2f(p0[0])    + v0);
                    p0[512]  = f2bf(bf2f(p0[512])  + v1);
                    p0[1024] = f2bf(bf2f(p0[1024]) + v2);
                    p0[1536] = f2bf(bf2f(p0[1536]) + v3);
                } else {
                    p0[0] = f2bf(v0); p0[512] = f2bf(v1);
                    p0[1024] = f2bf(v2); p0[1536] = f2bf(v3);
                }
            }
        }
    }
}

// ---------------- final rank reduce (bf16 s) ----------------
__global__ void reduce1_kernel(const unsigned short* __restrict__ s, const float* __restrict__ rw,
                               float* __restrict__ part) {
    int bo = blockIdx.x;
    int p = blockIdx.y;
    int t = threadIdx.x;
    const unsigned int* s0 = (const unsigned int*)(s + (size_t)(2 * bo) * 524288 + (size_t)p * 65536);
    const unsigned int* s1 = (const unsigned int*)(s + (size_t)(2 * bo) * 524288 + 524288 + (size_t)p * 65536);
    const float* rwp = rw + (size_t)p * 65536;
    float acc = 0.f;
    for (int j = t; j < 32768; j += 256) {
        unsigned int a = s0[j], b = s1[j];
        float2 rv = *(const float2*)(rwp + 2 * j);
        float x0 = fmaxf(__uint_as_float(a << 16), __uint_as_float(b << 16));
        float x1 = fmaxf(__uint_as_float(a & 0xFFFF0000u), __uint_as_float(b & 0xFFFF0000u));
        acc += rv.x * x0 + rv.y * x1;
    }
    __shared__ float red[256];
    red[t] = acc; __syncthreads();
    for (int ss = 128; ss; ss >>= 1) { if (t < ss) red[t] += red[t + ss]; __syncthreads(); }
    if (t == 0) part[bo * 8 + p] = red[0];
}

__global__ void reduce2_kernel(const float* __restrict__ part, const float* __restrict__ rb,
                               float* __restrict__ out) {
    int t = threadIdx.x;
    float a = rb[0];
    for (int p = 0; p < 8; p++) a += part[t * 8 + p];
    out[t] = a;
}

extern "C" void kernel_launch(void* const* d_in, const int* in_sizes, int n_in,
                              void* d_out, int out_size, void* d_ws, size_t ws_size,
                              hipStream_t stream) {
    const int* question = (const int*)d_in[0];
    const int* article  = (const int*)d_in[1];
    const float* emb    = (const float*)d_in[2];
    const float* g1_wih = (const float*)d_in[3];
    const float* g1_whh = (const float*)d_in[4];
    const float* g1_bih = (const float*)d_in[5];
    const float* g1_bhh = (const float*)d_in[6];
    const float* g2_wih = (const float*)d_in[7];
    const float* g2_whh = (const float*)d_in[8];
    const float* g2_bih = (const float*)d_in[9];
    const float* g2_bhh = (const float*)d_in[10];
    const float* b1_w   = (const float*)d_in[11];
    const float* b1_b   = (const float*)d_in[12];
    const float* b2_w   = (const float*)d_in[13];
    const float* b2_b   = (const float*)d_in[14];
    const float* rank_w = (const float*)d_in[15];
    const float* rank_b = (const float*)d_in[16];
    float* ws = (float*)d_ws;
    float* out = (float*)d_out;

    // ---- workspace layout (float offsets; phase-liveness verified) ----
    unsigned short* WPK1  = (unsigned short*)(ws);
    unsigned short* WIH1B = (unsigned short*)(ws + 196608);
    unsigned short* WPK2  = (unsigned short*)(ws + 393216);
    unsigned short* WIH2B = (unsigned short*)(ws + 589824);
    float* RM   = ws + 2195456;
    float* BBv  = ws + 2211840;
    float* Q2C  = ws + 2228224;
    float* PART = ws + 2260992;
    unsigned short* XEMBB = (unsigned short*)(ws + 2293760);
    float*          SMAT  = ws + 2293760;
    unsigned short* GI2B  = (unsigned short*)(ws + 2293760);
    float*          HBUF  = ws + 6488064;
    float*          AX2   = ws + 14876672;
    unsigned short* ATTB  = (unsigned short*)(ws + 25165824);
    unsigned short* GI1B  = (unsigned short*)(ws + 25165824);

    // 1. embed (bf16) + pack all weights to bf16 (single launch)
    embed_kernel<<<32768, 256, 0, stream>>>(question, article, emb, XEMBB);
    pack_weights<<<2112, 256, 0, stream>>>(g1_whh, g1_wih, g2_whh, g2_wih,
                                           WPK1, WIH1B, WPK2, WIH2B);

    // 2. GRU1 input gates, both dirs fused: M=32768 N=1536 K=256
    gemm_2dir<<<dim3(256, 12), 256, 0, stream>>>(
        XEMBB, WIH1B, g1_bih, GI1B, GI1B + (size_t)25165824, 0, 256);
    // 3. GRU1 scan
    gru_scan_rreg<<<256, 512, 0, stream>>>(GI1B, GI1B + (size_t)25165824, WPK1, g1_bhh, HBUF);

    float* QH = HBUF;
    float* AH = HBUF + (size_t)64 * 256 * 512;

    // 4. BiDAF1: c=QH, q=AH -> ATTB bf16 (set)
    {
        smat_mfma<<<dim3(2, 2, 64), 256, 0, stream>>>(QH, AH, b1_w, b1_b, SMAT);
        softmax_kernel<<<16384, 64, 0, stream>>>(SMAT, RM);
        bb_kernel<<<64, 256, 0, stream>>>(RM, BBv);
        q2c_kernel<<<dim3(64, 4), 128, 0, stream>>>(BBv, QH, Q2C);
        c2q_fix_mfma<<<dim3(2, 4, 64), 256, 0, stream>>>(SMAT, AH, QH, Q2C, ATTB, 0);
    }

    // 5. GRU2 input gates: reads bf16 ATTB directly, M=16384 N=1536 K=2048
    gemm_2dir<<<dim3(128, 12), 256, 0, stream>>>(
        ATTB, WIH2B, g2_bih, GI2B, GI2B + (size_t)12582912, 0, 2048);
    // 6. GRU2 scan
    gru_scan_rreg<<<128, 512, 0, stream>>>(GI2B, GI2B + (size_t)12582912, WPK2, g2_bhh, AX2);

    // 7. BiDAF2: c=q=AX2 -> ATTB (bf16 accumulate)
    {
        smat_mfma<<<dim3(2, 2, 64), 256, 0, stream>>>(AX2, AX2, b2_w, b2_b, SMAT);
        softmax_kernel<<<16384, 64, 0, stream>>>(SMAT, RM);
        bb_kernel<<<64, 256, 0, stream>>>(RM, BBv);
        q2c_kernel<<<dim3(64, 4), 128, 0, stream>>>(BBv, AX2, Q2C);
        c2q_fix_mfma<<<dim3(2, 4, 64), 256, 0, stream>>>(SMAT, AX2, AX2, Q2C, ATTB, 1);
    }

    // 8. rank reduce (bf16 s)
    reduce1_kernel<<<dim3(32, 8), 256, 0, stream>>>(ATTB, rank_w, PART);
    reduce2_kernel<<<1, 32, 0, stream>>>(PART, rank_b, out);
}

// Round 12
// 1177.395 us; speedup vs baseline: 1.3526x; 1.3526x over previous
//
#include <hip/hip_runtime.h>
#include <math.h>

#define LSEQ 256
#define HID 256
#define H2 512
#define H3 768
#define H8 2048

typedef __attribute__((ext_vector_type(8))) short short8;
typedef __attribute__((ext_vector_type(4))) float floatx4;

__device__ __forceinline__ unsigned short f2bf(float f) {
    unsigned int u = __float_as_uint(f);
    u = (u + 0x7FFFu + ((u >> 16) & 1u)) >> 16;
    return (unsigned short)u;
}
__device__ __forceinline__ float bf2f(unsigned short h) {
    return __uint_as_float(((unsigned int)h) << 16);
}
__device__ __forceinline__ float fsig(float x) {
    return __builtin_amdgcn_rcpf(1.f + __expf(-x));
}
__device__ __forceinline__ float ftanh(float x) {
    return __builtin_fmaf(2.f, __builtin_amdgcn_rcpf(1.f + __expf(-2.f * x)), -1.f);
}
// async global->LDS 16B per lane: LDS dest = base + lane*16 (wave-uniform base)
__device__ __forceinline__ void gload_lds16(const void* g, void* l) {
    __builtin_amdgcn_global_load_lds(
        (const __attribute__((address_space(1))) unsigned int*)g,
        (__attribute__((address_space(3))) unsigned int*)l, 16, 0, 0);
}

// ---------------- embed (bf16 out) ----------------
__global__ void embed_kernel(const int* __restrict__ question,
                             const int* __restrict__ article,
                             const float* __restrict__ emb,
                             unsigned short* __restrict__ xemb) {
    int gid = blockIdx.x * 256 + threadIdx.x;   // 128*256*256
    int d = gid & 255;
    int rl = gid >> 8;
    int l = rl & 255;
    int stream = rl >> 8;
    int id;
    if (stream < 64) {
        int b = stream >> 3, o = (stream & 7) >> 1;
        id = question[(b * 4 + o) * 256 + l];
    } else {
        id = article[(stream - 64) * 256 + l];
    }
    xemb[(size_t)gid] = f2bf(emb[(size_t)id * 256 + d]);
}

// all 4 weight tensors in one launch (3 x 49152 + 393216 = 540672 uint4-units)
__global__ void pack_weights(const float* __restrict__ g1whh, const float* __restrict__ g1wih,
                             const float* __restrict__ g2whh, const float* __restrict__ g2wih,
                             unsigned short* __restrict__ wpk1, unsigned short* __restrict__ wih1,
                             unsigned short* __restrict__ wpk2, unsigned short* __restrict__ wih2) {
    int i = blockIdx.x * 256 + threadIdx.x;
    const float* src; unsigned short* dst; int j;
    if (i < 49152)       { src = g1whh; dst = wpk1; j = i; }
    else if (i < 98304)  { src = g1wih; dst = wih1; j = i - 49152; }
    else if (i < 147456) { src = g2whh; dst = wpk2; j = i - 98304; }
    else if (i < 540672) { src = g2wih; dst = wih2; j = i - 147456; }
    else return;
    float4 a = ((const float4*)src)[2 * j];
    float4 b = ((const float4*)src)[2 * j + 1];
    uint4 o;
    o.x = (unsigned int)f2bf(a.x) | ((unsigned int)f2bf(a.y) << 16);
    o.y = (unsigned int)f2bf(a.z) | ((unsigned int)f2bf(a.w) << 16);
    o.z = (unsigned int)f2bf(b.x) | ((unsigned int)f2bf(b.y) << 16);
    o.w = (unsigned int)f2bf(b.z) | ((unsigned int)f2bf(b.w) << 16);
    ((uint4*)dst)[j] = o;
}

// ---------------- MFMA GEMM, both GRU dirs fused; global_load_lds staging ----------------
__global__ __launch_bounds__(256)
void gemm_2dir(const unsigned short* __restrict__ A, const unsigned short* __restrict__ B,
               const float* __restrict__ bias, unsigned short* __restrict__ C0,
               unsigned short* __restrict__ C1, int mbase, int K) {
    __shared__ __align__(16) unsigned short At[128][32];
    __shared__ __align__(16) unsigned short Bt[128][32];
    int tid = threadIdx.x;
    int m0 = blockIdx.x * 128, n0 = blockIdx.y * 128;
    int l = tid & 63, w = tid >> 6;          // 4 waves
    int wm = (w & 1) * 64, wn = (w >> 1) * 64;
    int lr = l & 15, kq = l >> 4;
    int subrow = l >> 2;
    int swc = (l & 3) ^ (subrow & 3);
    const unsigned short* gA0 = A + (size_t)(m0 + w * 32 + subrow) * K + swc * 8;
    const unsigned short* gA1 = A + (size_t)(m0 + w * 32 + 16 + subrow) * K + swc * 8;
    const unsigned short* gB0 = B + (size_t)(n0 + w * 32 + subrow) * K + swc * 8;
    const unsigned short* gB1 = B + (size_t)(n0 + w * 32 + 16 + subrow) * K + swc * 8;
    unsigned short* lA0 = &At[w * 32][0];
    unsigned short* lA1 = &At[w * 32 + 16][0];
    unsigned short* lB0 = &Bt[w * 32][0];
    unsigned short* lB1 = &Bt[w * 32 + 16][0];
    int rchunk = (kq ^ (lr & 3)) * 8;
    floatx4 acc[4][4];
#pragma unroll
    for (int i = 0; i < 4; i++)
#pragma unroll
        for (int j = 0; j < 4; j++) acc[i][j] = (floatx4){0.f, 0.f, 0.f, 0.f};
    for (int k0 = 0; k0 < K; k0 += 32) {
        __syncthreads();
        gload_lds16(gA0 + k0, lA0);
        gload_lds16(gA1 + k0, lA1);
        gload_lds16(gB0 + k0, lB0);
        gload_lds16(gB1 + k0, lB1);
        __syncthreads();
        short8 af[4], bf[4];
#pragma unroll
        for (int i = 0; i < 4; i++) {
            af[i] = *(const short8*)&At[wm + i * 16 + lr][rchunk];
            bf[i] = *(const short8*)&Bt[wn + i * 16 + lr][rchunk];
        }
#pragma unroll
        for (int i = 0; i < 4; i++)
#pragma unroll
            for (int j = 0; j < 4; j++)
                acc[i][j] = __builtin_amdgcn_mfma_f32_16x16x32_bf16(af[i], bf[j], acc[i][j], 0, 0, 0);
    }
    int quad = l >> 4;
#pragma unroll
    for (int i = 0; i < 4; i++) {
#pragma unroll
        for (int j = 0; j < 4; j++) {
            int n = n0 + wn + j * 16 + lr;
            float bs = bias[n];
            unsigned short* dst = (n < 768) ? C0 : C1;
            int nn = (n < 768) ? n : n - 768;
#pragma unroll
            for (int r = 0; r < 4; r++) {
                int m = mbase + m0 + wm + i * 16 + quad * 4 + r;
                dst[(size_t)m * 768 + nn] = f2bf(acc[i][j][r] + bs);
            }
        }
    }
}

// ---------------- GRU scan: 1 stream/block, whh in VGPRs, in-wave gates ----------------
// R12: reverted to the R10 structure (6x8-deep chains). R11's 2-way acc split
// pushed VGPRs over the 128 cap -> scratch spill (FETCH/WRITE up, 307->517us).
__global__ __launch_bounds__(512, 2)
void gru_scan_rreg(const unsigned short* __restrict__ gi_f,
                   const unsigned short* __restrict__ gi_b,
                   const unsigned short* __restrict__ whh_bf,
                   const float* __restrict__ bhh,
                   float* __restrict__ out) {
    int blk = blockIdx.x;
    int d = blk & 1, s = blk >> 1;
    const unsigned short* gi_blk = (d ? gi_b : gi_f) + (size_t)s * LSEQ * H3;
    const unsigned short* wb = whh_bf + (size_t)d * H3 * HID;

    __shared__ __align__(16) unsigned short h_pack[2][256];  // double-buffered h (bf16)

    int tid = threadIdx.x;
    int lane = tid & 63, wave = tid >> 6;
    int lr = lane & 15, kq = lane >> 4;

    short8 bq[6][8];
#pragma unroll
    for (int nt = 0; nt < 6; nt++) {
        int row = (nt >> 1) * 256 + wave * 32 + (nt & 1) * 16 + lr;
        const unsigned short* wp = wb + (size_t)row * HID + kq * 8;
#pragma unroll
        for (int kt = 0; kt < 8; kt++)
            bq[nt][kt] = *(const short8*)(wp + kt * 32);
    }

    int hh0 = wave * 32 + lr, hh1 = hh0 + 16;
    float br0 = bhh[d * H3 + hh0],       br1 = bhh[d * H3 + hh1];
    float bz0 = bhh[d * H3 + 256 + hh0], bz1 = bhh[d * H3 + 256 + hh1];
    float bn0 = bhh[d * H3 + 512 + hh0], bn1 = bhh[d * H3 + 512 + hh1];

    int t0 = d ? (LSEQ - 1) : 0;
    int tstep = d ? -1 : 1;

    if (tid < 128) ((unsigned int*)h_pack[0])[tid] = 0;
    float hold0 = 0.f, hold1 = 0.f;

    unsigned short gr0, gz0, gn0, gr1, gz1, gn1;
    {
        const unsigned short* gp = gi_blk + (size_t)t0 * H3;
        gr0 = gp[hh0]; gz0 = gp[256 + hh0]; gn0 = gp[512 + hh0];
        gr1 = gp[hh1]; gz1 = gp[256 + hh1]; gn1 = gp[512 + hh1];
    }
    __syncthreads();

    int cur = 0, t = t0;
    for (int step = 0; step < LSEQ; ++step) {
        unsigned short nr0 = 0, nz0 = 0, nn0 = 0, nr1 = 0, nz1 = 0, nn1 = 0;
        if (step + 1 < LSEQ) {
            const unsigned short* gp = gi_blk + (size_t)(t + tstep) * H3;
            nr0 = gp[hh0]; nz0 = gp[256 + hh0]; nn0 = gp[512 + hh0];
            nr1 = gp[hh1]; nz1 = gp[256 + hh1]; nn1 = gp[512 + hh1];
        }
        floatx4 acc[6];
#pragma unroll
        for (int nt = 0; nt < 6; nt++) acc[nt] = (floatx4){0.f, 0.f, 0.f, 0.f};
#pragma unroll
        for (int kt = 0; kt < 8; kt++) {
            short8 av = *(const short8*)&h_pack[cur][kt * 32 + kq * 8];  // broadcast
#pragma unroll
            for (int nt = 0; nt < 6; nt++)
                acc[nt] = __builtin_amdgcn_mfma_f32_16x16x32_bf16(av, bq[nt][kt], acc[nt], 0, 0, 0);
        }
        float rg0 = fsig(bf2f(gr0) + acc[0][0] + br0);
        float rg1 = fsig(bf2f(gr1) + acc[1][0] + br1);
        float zg0 = fsig(bf2f(gz0) + acc[2][0] + bz0);
        float zg1 = fsig(bf2f(gz1) + acc[3][0] + bz1);
        float ng0 = ftanh(bf2f(gn0) + rg0 * (acc[4][0] + bn0));
        float ng1 = ftanh(bf2f(gn1) + rg1 * (acc[5][0] + bn1));
        float h0 = (1.f - zg0) * ng0 + zg0 * hold0;
        float h1 = (1.f - zg1) * ng1 + zg1 * hold1;
        hold0 = h0; hold1 = h1;
        int nxt = cur ^ 1;
        if (kq == 0) {
            h_pack[nxt][hh0] = f2bf(h0);
            h_pack[nxt][hh1] = f2bf(h1);
            float* op = out + ((size_t)s * LSEQ + t) * H2 + d * HID;
            op[hh0] = h0;
            op[hh1] = h1;
        }
        gr0 = nr0; gz0 = nz0; gn0 = nn0;
        gr1 = nr1; gz1 = nz1; gn1 = nn1;
        __syncthreads();
        cur = nxt; t += tstep;
    }
}

// ---------------- smat via MFMA split-bf16 (trunc-split), FUSED cw/qw dots ----------------
// S[m][n] = sum_k (c[m][k]*w2[k]) * q[n][k] + cw[m] + qw[n] + bsum
// trunc-split: hi = top-16 bits (1 op), lo = rne-bf16(x - hi); hi+lo ~ x to 2^-17.
__global__ __launch_bounds__(256)
void smat_mfma(const float* __restrict__ c, const float* __restrict__ q,
               const float* __restrict__ w1, const float* __restrict__ bvec,
               float* __restrict__ smat) {
    __shared__ __align__(16) unsigned short Ah[128][40];
    __shared__ __align__(16) unsigned short Al[128][40];
    __shared__ __align__(16) unsigned short Bh[128][40];
    __shared__ __align__(16) unsigned short Bl[128][40];
    __shared__ float cwl[128];
    __shared__ float qwl[128];
    const float* w2 = w1 + 1024;
    int b = blockIdx.z;
    int m0 = blockIdx.x * 128, n0 = blockIdx.y * 128;
    int tid = threadIdx.x;
    int l = tid & 63, w = tid >> 6;
    int wm = (w & 1) * 64, wn = (w >> 1) * 64;
    int lr = l & 15, koff = (l >> 4) * 8;
    int srow = tid >> 1, scol = (tid & 1) * 16;
    floatx4 acc[4][4];
#pragma unroll
    for (int i = 0; i < 4; i++)
#pragma unroll
        for (int j = 0; j < 4; j++) acc[i][j] = (floatx4){0.f, 0.f, 0.f, 0.f};
    const float* ap0 = c + (size_t)(b * 256 + m0 + srow) * H2 + scol;
    const float* bp0 = q + (size_t)(b * 256 + n0 + srow) * H2 + scol;
    float pcw = 0.f, pqw = 0.f;
    for (int k0 = 0; k0 < H2; k0 += 32) {
        float av[16], bv[16], wv[16], wc[16], wq[16];
        *(float4*)&av[0]  = *(const float4*)(ap0 + k0);
        *(float4*)&av[4]  = *(const float4*)(ap0 + k0 + 4);
        *(float4*)&av[8]  = *(const float4*)(ap0 + k0 + 8);
        *(float4*)&av[12] = *(const float4*)(ap0 + k0 + 12);
        *(float4*)&bv[0]  = *(const float4*)(bp0 + k0);
        *(float4*)&bv[4]  = *(const float4*)(bp0 + k0 + 4);
        *(float4*)&bv[8]  = *(const float4*)(bp0 + k0 + 8);
        *(float4*)&bv[12] = *(const float4*)(bp0 + k0 + 12);
        *(float4*)&wv[0]  = *(const float4*)(w2 + k0 + scol);
        *(float4*)&wv[4]  = *(const float4*)(w2 + k0 + scol + 4);
        *(float4*)&wv[8]  = *(const float4*)(w2 + k0 + scol + 8);
        *(float4*)&wv[12] = *(const float4*)(w2 + k0 + scol + 12);
        *(float4*)&wc[0]  = *(const float4*)(w1 + k0 + scol);
        *(float4*)&wc[4]  = *(const float4*)(w1 + k0 + scol + 4);
        *(float4*)&wc[8]  = *(const float4*)(w1 + k0 + scol + 8);
        *(float4*)&wc[12] = *(const float4*)(w1 + k0 + scol + 12);
        *(float4*)&wq[0]  = *(const float4*)(w1 + 512 + k0 + scol);
        *(float4*)&wq[4]  = *(const float4*)(w1 + 512 + k0 + scol + 4);
        *(float4*)&wq[8]  = *(const float4*)(w1 + 512 + k0 + scol + 8);
        *(float4*)&wq[12] = *(const float4*)(w1 + 512 + k0 + scol + 12);
#pragma unroll
        for (int j = 0; j < 16; j++) { pcw += av[j] * wc[j]; pqw += bv[j] * wq[j]; }
        unsigned int ahw[8], alw[8], bhw[8], blw[8];
#pragma unroll
        for (int j = 0; j < 8; j++) {
            float a0 = av[2 * j] * wv[2 * j], a1 = av[2 * j + 1] * wv[2 * j + 1];
            unsigned int u0 = __float_as_uint(a0), u1 = __float_as_uint(a1);
            ahw[j] = (u0 >> 16) | (u1 & 0xFFFF0000u);
            float r0 = a0 - __uint_as_float(u0 & 0xFFFF0000u);
            float r1 = a1 - __uint_as_float(u1 & 0xFFFF0000u);
            alw[j] = (unsigned int)f2bf(r0) | ((unsigned int)f2bf(r1) << 16);
            unsigned int v0 = __float_as_uint(bv[2 * j]), v1 = __float_as_uint(bv[2 * j + 1]);
            bhw[j] = (v0 >> 16) | (v1 & 0xFFFF0000u);
            float s0 = bv[2 * j]     - __uint_as_float(v0 & 0xFFFF0000u);
            float s1 = bv[2 * j + 1] - __uint_as_float(v1 & 0xFFFF0000u);
            blw[j] = (unsigned int)f2bf(s0) | ((unsigned int)f2bf(s1) << 16);
        }
        __syncthreads();
        *(uint4*)&Ah[srow][scol]     = *(uint4*)&ahw[0];
        *(uint4*)&Ah[srow][scol + 8] = *(uint4*)&ahw[4];
        *(uint4*)&Al[srow][scol]     = *(uint4*)&alw[0];
        *(uint4*)&Al[srow][scol + 8] = *(uint4*)&alw[4];
        *(uint4*)&Bh[srow][scol]     = *(uint4*)&bhw[0];
        *(uint4*)&Bh[srow][scol + 8] = *(uint4*)&bhw[4];
        *(uint4*)&Bl[srow][scol]     = *(uint4*)&blw[0];
        *(uint4*)&Bl[srow][scol + 8] = *(uint4*)&blw[4];
        __syncthreads();
        short8 afh[4], afl[4], bfh[4], bfl[4];
#pragma unroll
        for (int i = 0; i < 4; i++) {
            afh[i] = *(const short8*)&Ah[wm + i * 16 + lr][koff];
            afl[i] = *(const short8*)&Al[wm + i * 16 + lr][koff];
            bfh[i] = *(const short8*)&Bh[wn + i * 16 + lr][koff];
            bfl[i] = *(const short8*)&Bl[wn + i * 16 + lr][koff];
        }
#pragma unroll
        for (int i = 0; i < 4; i++)
#pragma unroll
            for (int j = 0; j < 4; j++) {
                acc[i][j] = __builtin_amdgcn_mfma_f32_16x16x32_bf16(afl[i], bfh[j], acc[i][j], 0, 0, 0);
                acc[i][j] = __builtin_amdgcn_mfma_f32_16x16x32_bf16(afh[i], bfl[j], acc[i][j], 0, 0, 0);
                acc[i][j] = __builtin_amdgcn_mfma_f32_16x16x32_bf16(afh[i], bfh[j], acc[i][j], 0, 0, 0);
            }
    }
    // pair-reduce the cw/qw partial dots (lanes tid, tid^1 share srow)
    pcw += __shfl_xor(pcw, 1);
    pqw += __shfl_xor(pqw, 1);
    if ((tid & 1) == 0) { cwl[srow] = pcw; qwl[srow] = pqw; }
    __syncthreads();
    float bsum = bvec[0] + bvec[1] + bvec[2];
    int quad = l >> 4;
#pragma unroll
    for (int i = 0; i < 4; i++) {
#pragma unroll
        for (int j = 0; j < 4; j++) {
            int n = n0 + wn + j * 16 + lr;
            float qwv = qwl[wn + j * 16 + lr] + bsum;
#pragma unroll
            for (int r = 0; r < 4; r++) {
                int m = m0 + wm + i * 16 + quad * 4 + r;
                smat[((size_t)(b * 256 + m)) * 256 + n] =
                    acc[i][j][r] + cwl[wm + i * 16 + quad * 4 + r] + qwv;
            }
        }
    }
}

__global__ void softmax_kernel(float* __restrict__ smat, float* __restrict__ rowmax) {
    int row = blockIdx.x;
    int lane = threadIdx.x;
    float* p = smat + (size_t)row * LSEQ;
    float v[4];
    float mx = -1e30f;
#pragma unroll
    for (int j = 0; j < 4; j++) { v[j] = p[lane + j * 64]; mx = fmaxf(mx, v[j]); }
    for (int off = 32; off; off >>= 1) mx = fmaxf(mx, __shfl_down(mx, off));
    mx = __shfl(mx, 0);
    float sum = 0.f;
#pragma unroll
    for (int j = 0; j < 4; j++) { v[j] = __expf(v[j] - mx); sum += v[j]; }
    for (int off = 32; off; off >>= 1) sum += __shfl_down(sum, off);
    sum = __shfl(sum, 0);
    float inv = 1.f / sum;
#pragma unroll
    for (int j = 0; j < 4; j++) p[lane + j * 64] = v[j] * inv;
    if (lane == 0) rowmax[row] = mx;
}

__global__ void bb_kernel(const float* __restrict__ rowmax, float* __restrict__ bb) {
    int b = blockIdx.x; int t = threadIdx.x;
    __shared__ float red[256];
    float v = rowmax[b * LSEQ + t];
    red[t] = v; __syncthreads();
    for (int s = 128; s; s >>= 1) { if (t < s) red[t] = fmaxf(red[t], red[t + s]); __syncthreads(); }
    float mx = red[0]; __syncthreads();
    float e = __expf(v - mx);
    red[t] = e; __syncthreads();
    for (int s = 128; s; s >>= 1) { if (t < s) red[t] += red[t + s]; __syncthreads(); }
    bb[b * LSEQ + t] = e / red[0];
}

// q2c: grid (64,4) x 128 thr; 4 independent accumulators break the add chain
__global__ void q2c_kernel(const float* __restrict__ bb, const float* __restrict__ c,
                           float* __restrict__ q2c) {
    int b = blockIdx.x;
    int d = blockIdx.y * 128 + threadIdx.x;
    const float* cb = c + (size_t)b * LSEQ * H2 + d;
    const float* bbp = bb + b * LSEQ;
    float a0 = 0.f, a1 = 0.f, a2 = 0.f, a3 = 0.f;
    for (int i = 0; i < LSEQ; i += 4) {
        a0 += bbp[i]     * cb[(size_t)i * H2];
        a1 += bbp[i + 1] * cb[(size_t)(i + 1) * H2];
        a2 += bbp[i + 2] * cb[(size_t)(i + 2) * H2];
        a3 += bbp[i + 3] * cb[(size_t)(i + 3) * H2];
    }
    q2c[b * H2 + d] = (a0 + a1) + (a2 + a3);
}

// c2q via MFMA split-bf16 (trunc-split) with FUSED fixup03 epilogue; ATT bf16.
__global__ __launch_bounds__(256)
void c2q_fix_mfma(const float* __restrict__ amat, const float* __restrict__ q,
                  const float* __restrict__ c, const float* __restrict__ q2c,
                  unsigned short* __restrict__ att, int add) {
    __shared__ __align__(16) unsigned short Ah[128][40];
    __shared__ __align__(16) unsigned short Al[128][40];
    __shared__ __align__(16) unsigned short Bh[128][40];
    __shared__ __align__(16) unsigned short Bl[128][40];
    int b = blockIdx.z;
    int m0 = blockIdx.x * 128, n0 = blockIdx.y * 128;
    int tid = threadIdx.x;
    int l = tid & 63, w = tid >> 6;
    int wm = (w & 1) * 64, wn = (w >> 1) * 64;
    int lr = l & 15, koff = (l >> 4) * 8;
    int srow = tid >> 1, scol = (tid & 1) * 16;
    int bn = tid & 127, bkh = tid >> 7;           // B-stage: column n0+bn, k-half bkh
    floatx4 acc[4][4];
#pragma unroll
    for (int i = 0; i < 4; i++)
#pragma unroll
        for (int j = 0; j < 4; j++) acc[i][j] = (floatx4){0.f, 0.f, 0.f, 0.f};
    for (int k0 = 0; k0 < LSEQ; k0 += 32) {
        float av[16];
        const float* ap = amat + (size_t)(b * 256 + m0 + srow) * 256 + k0 + scol;
        *(float4*)&av[0]  = *(const float4*)(ap);
        *(float4*)&av[4]  = *(const float4*)(ap + 4);
        *(float4*)&av[8]  = *(const float4*)(ap + 8);
        *(float4*)&av[12] = *(const float4*)(ap + 12);
        float qv[16];
        const float* qp = q + (size_t)(b * 256 + k0 + bkh * 16) * H2 + n0 + bn;
#pragma unroll
        for (int j = 0; j < 16; j++) qv[j] = qp[(size_t)j * H2];
        unsigned int ahw[8], alw[8], bhw[8], blw[8];
#pragma unroll
        for (int j = 0; j < 8; j++) {
            unsigned int u0 = __float_as_uint(av[2 * j]), u1 = __float_as_uint(av[2 * j + 1]);
            ahw[j] = (u0 >> 16) | (u1 & 0xFFFF0000u);
            float r0 = av[2 * j]     - __uint_as_float(u0 & 0xFFFF0000u);
            float r1 = av[2 * j + 1] - __uint_as_float(u1 & 0xFFFF0000u);
            alw[j] = (unsigned int)f2bf(r0) | ((unsigned int)f2bf(r1) << 16);
            unsigned int v0 = __float_as_uint(qv[2 * j]), v1 = __float_as_uint(qv[2 * j + 1]);
            bhw[j] = (v0 >> 16) | (v1 & 0xFFFF0000u);
            float s0 = qv[2 * j]     - __uint_as_float(v0 & 0xFFFF0000u);
            float s1 = qv[2 * j + 1] - __uint_as_float(v1 & 0xFFFF0000u);
            blw[j] = (unsigned int)f2bf(s0) | ((unsigned int)f2bf(s1) << 16);
        }
        __syncthreads();
        *(uint4*)&Ah[srow][scol]         = *(uint4*)&ahw[0];
        *(uint4*)&Ah[srow][scol + 8]     = *(uint4*)&ahw[4];
        *(uint4*)&Al[srow][scol]         = *(uint4*)&alw[0];
        *(uint4*)&Al[srow][scol + 8]     = *(uint4*)&alw[4];
        *(uint4*)&Bh[bn][bkh * 16]       = *(uint4*)&bhw[0];
        *(uint4*)&Bh[bn][bkh * 16 + 8]   = *(uint4*)&bhw[4];
        *(uint4*)&Bl[bn][bkh * 16]       = *(uint4*)&blw[0];
        *(uint4*)&Bl[bn][bkh * 16 + 8]   = *(uint4*)&blw[4];
        __syncthreads();
        short8 afh[4], afl[4], bfh[4], bfl[4];
#pragma unroll
        for (int i = 0; i < 4; i++) {
            afh[i] = *(const short8*)&Ah[wm + i * 16 + lr][koff];
            afl[i] = *(const short8*)&Al[wm + i * 16 + lr][koff];
            bfh[i] = *(const short8*)&Bh[wn + i * 16 + lr][koff];
            bfl[i] = *(const short8*)&Bl[wn + i * 16 + lr][koff];
        }
#pragma unroll
        for (int i = 0; i < 4; i++)
#pragma unroll
            for (int j = 0; j < 4; j++) {
                acc[i][j] = __builtin_amdgcn_mfma_f32_16x16x32_bf16(afl[i], bfh[j], acc[i][j], 0, 0, 0);
                acc[i][j] = __builtin_amdgcn_mfma_f32_16x16x32_bf16(afh[i], bfl[j], acc[i][j], 0, 0, 0);
                acc[i][j] = __builtin_amdgcn_mfma_f32_16x16x32_bf16(afh[i], bfh[j], acc[i][j], 0, 0, 0);
            }
    }
    int quad = l >> 4;
#pragma unroll
    for (int i = 0; i < 4; i++) {
#pragma unroll
        for (int j = 0; j < 4; j++) {
            int n = n0 + wn + j * 16 + lr;
            float q2cv = q2c[b * H2 + n];
#pragma unroll
            for (int r = 0; r < 4; r++) {
                int m = m0 + wm + i * 16 + quad * 4 + r;
                size_t row = (size_t)b * 256 + m;
                float a = acc[i][j][r];
                float cv = c[row * H2 + n];
                float v0 = fmaxf(cv, 0.f);
                float v1 = fmaxf(a, 0.f);
                float v2 = fmaxf(cv * a, 0.f);
                float v3 = fmaxf(cv * q2cv, 0.f);
                unsigned short* p0 = att + row * H8 + n;
                if (add) {
                    p0[0]    = f2bf(bf2f(p0[0])    + v0);
                    p0[512]  = f2bf(bf2f(p0[512])  + v1);
                    p0[1024] = f2bf(bf2f(p0[1024]) + v2);
                    p0[1536] = f2bf(bf2f(p0[1536]) + v3);
                } else {
                    p0[0] = f2bf(v0); p0[512] = f2bf(v1);
                    p0[1024] = f2bf(v2); p0[1536] = f2bf(v3);
                }
            }
        }
    }
}

// ---------------- final rank reduce (bf16 s) ----------------
__global__ void reduce1_kernel(const unsigned short* __restrict__ s, const float* __restrict__ rw,
                               float* __restrict__ part) {
    int bo = blockIdx.x;
    int p = blockIdx.y;
    int t = threadIdx.x;
    const unsigned int* s0 = (const unsigned int*)(s + (size_t)(2 * bo) * 524288 + (size_t)p * 65536);
    const unsigned int* s1 = (const unsigned int*)(s + (size_t)(2 * bo) * 524288 + 524288 + (size_t)p * 65536);
    const float* rwp = rw + (size_t)p * 65536;
    float acc = 0.f;
    for (int j = t; j < 32768; j += 256) {
        unsigned int a = s0[j], b = s1[j];
        float2 rv = *(const float2*)(rwp + 2 * j);
        float x0 = fmaxf(__uint_as_float(a << 16), __uint_as_float(b << 16));
        float x1 = fmaxf(__uint_as_float(a & 0xFFFF0000u), __uint_as_float(b & 0xFFFF0000u));
        acc += rv.x * x0 + rv.y * x1;
    }
    __shared__ float red[256];
    red[t] = acc; __syncthreads();
    for (int ss = 128; ss; ss >>= 1) { if (t < ss) red[t] += red[t + ss]; __syncthreads(); }
    if (t == 0) part[bo * 8 + p] = red[0];
}

__global__ void reduce2_kernel(const float* __restrict__ part, const float* __restrict__ rb,
                               float* __restrict__ out) {
    int t = threadIdx.x;
    float a = rb[0];
    for (int p = 0; p < 8; p++) a += part[t * 8 + p];
    out[t] = a;
}

extern "C" void kernel_launch(void* const* d_in, const int* in_sizes, int n_in,
                              void* d_out, int out_size, void* d_ws, size_t ws_size,
                              hipStream_t stream) {
    const int* question = (const int*)d_in[0];
    const int* article  = (const int*)d_in[1];
    const float* emb    = (const float*)d_in[2];
    const float* g1_wih = (const float*)d_in[3];
    const float* g1_whh = (const float*)d_in[4];
    const float* g1_bih = (const float*)d_in[5];
    const float* g1_bhh = (const float*)d_in[6];
    const float* g2_wih = (const float*)d_in[7];
    const float* g2_whh = (const float*)d_in[8];
    const float* g2_bih = (const float*)d_in[9];
    const float* g2_bhh = (const float*)d_in[10];
    const float* b1_w   = (const float*)d_in[11];
    const float* b1_b   = (const float*)d_in[12];
    const float* b2_w   = (const float*)d_in[13];
    const float* b2_b   = (const float*)d_in[14];
    const float* rank_w = (const float*)d_in[15];
    const float* rank_b = (const float*)d_in[16];
    float* ws = (float*)d_ws;
    float* out = (float*)d_out;

    // ---- workspace layout (float offsets; phase-liveness verified) ----
    unsigned short* WPK1  = (unsigned short*)(ws);
    unsigned short* WIH1B = (unsigned short*)(ws + 196608);
    unsigned short* WPK2  = (unsigned short*)(ws + 393216);
    unsigned short* WIH2B = (unsigned short*)(ws + 589824);
    float* RM   = ws + 2195456;
    float* BBv  = ws + 2211840;
    float* Q2C  = ws + 2228224;
    float* PART = ws + 2260992;
    unsigned short* XEMBB = (unsigned short*)(ws + 2293760);
    float*          SMAT  = ws + 2293760;
    unsigned short* GI2B  = (unsigned short*)(ws + 2293760);
    float*          HBUF  = ws + 6488064;
    float*          AX2   = ws + 14876672;
    unsigned short* ATTB  = (unsigned short*)(ws + 25165824);
    unsigned short* GI1B  = (unsigned short*)(ws + 25165824);

    // 1. embed (bf16) + pack all weights to bf16 (single launch)
    embed_kernel<<<32768, 256, 0, stream>>>(question, article, emb, XEMBB);
    pack_weights<<<2112, 256, 0, stream>>>(g1_whh, g1_wih, g2_whh, g2_wih,
                                           WPK1, WIH1B, WPK2, WIH2B);

    // 2. GRU1 input gates, both dirs fused: M=32768 N=1536 K=256
    gemm_2dir<<<dim3(256, 12), 256, 0, stream>>>(
        XEMBB, WIH1B, g1_bih, GI1B, GI1B + (size_t)25165824, 0, 256);
    // 3. GRU1 scan
    gru_scan_rreg<<<256, 512, 0, stream>>>(GI1B, GI1B + (size_t)25165824, WPK1, g1_bhh, HBUF);

    float* QH = HBUF;
    float* AH = HBUF + (size_t)64 * 256 * 512;

    // 4. BiDAF1: c=QH, q=AH -> ATTB bf16 (set)
    {
        smat_mfma<<<dim3(2, 2, 64), 256, 0, stream>>>(QH, AH, b1_w, b1_b, SMAT);
        softmax_kernel<<<16384, 64, 0, stream>>>(SMAT, RM);
        bb_kernel<<<64, 256, 0, stream>>>(RM, BBv);
        q2c_kernel<<<dim3(64, 4), 128, 0, stream>>>(BBv, QH, Q2C);
        c2q_fix_mfma<<<dim3(2, 4, 64), 256, 0, stream>>>(SMAT, AH, QH, Q2C, ATTB, 0);
    }

    // 5. GRU2 input gates: reads bf16 ATTB directly, M=16384 N=1536 K=2048
    gemm_2dir<<<dim3(128, 12), 256, 0, stream>>>(
        ATTB, WIH2B, g2_bih, GI2B, GI2B + (size_t)12582912, 0, 2048);
    // 6. GRU2 scan
    gru_scan_rreg<<<128, 512, 0, stream>>>(GI2B, GI2B + (size_t)12582912, WPK2, g2_bhh, AX2);

    // 7. BiDAF2: c=q=AX2 -> ATTB (bf16 accumulate)
    {
        smat_mfma<<<dim3(2, 2, 64), 256, 0, stream>>>(AX2, AX2, b2_w, b2_b, SMAT);
        softmax_kernel<<<16384, 64, 0, stream>>>(SMAT, RM);
        bb_kernel<<<64, 256, 0, stream>>>(RM, BBv);
        q2c_kernel<<<dim3(64, 4), 128, 0, stream>>>(BBv, AX2, Q2C);
        c2q_fix_mfma<<<dim3(2, 4, 64), 256, 0, stream>>>(SMAT, AX2, AX2, Q2C, ATTB, 1);
    }

    // 8. rank reduce (bf16 s)
    reduce1_kernel<<<dim3(32, 8), 256, 0, stream>>>(ATTB, rank_w, PART);
    reduce2_kernel<<<1, 32, 0, stream>>>(PART, rank_b, out);
}

// Round 13
// 1151.234 us; speedup vs baseline: 1.3834x; 1.0227x over previous
//
#include <hip/hip_runtime.h>
#include <math.h>

#define LSEQ 256
#define HID 256
#define H2 512
#define H3 768
#define H8 2048

typedef __attribute__((ext_vector_type(8))) short short8;
typedef __attribute__((ext_vector_type(4))) float floatx4;

__device__ __forceinline__ unsigned short f2bf(float f) {
    unsigned int u = __float_as_uint(f);
    u = (u + 0x7FFFu + ((u >> 16) & 1u)) >> 16;
    return (unsigned short)u;
}
__device__ __forceinline__ float bf2f(unsigned short h) {
    return __uint_as_float(((unsigned int)h) << 16);
}
__device__ __forceinline__ float fsig(float x) {
    return __builtin_amdgcn_rcpf(1.f + __expf(-x));
}
__device__ __forceinline__ float ftanh(float x) {
    return __builtin_fmaf(2.f, __builtin_amdgcn_rcpf(1.f + __expf(-2.f * x)), -1.f);
}
// async global->LDS 16B per lane: LDS dest = base + lane*16 (wave-uniform base)
__device__ __forceinline__ void gload_lds16(const void* g, void* l) {
    __builtin_amdgcn_global_load_lds(
        (const __attribute__((address_space(1))) unsigned int*)g,
        (__attribute__((address_space(3))) unsigned int*)l, 16, 0, 0);
}

// ---------------- embed (bf16 out) ----------------
__global__ void embed_kernel(const int* __restrict__ question,
                             const int* __restrict__ article,
                             const float* __restrict__ emb,
                             unsigned short* __restrict__ xemb) {
    int gid = blockIdx.x * 256 + threadIdx.x;   // 128*256*256
    int d = gid & 255;
    int rl = gid >> 8;
    int l = rl & 255;
    int stream = rl >> 8;
    int id;
    if (stream < 64) {
        int b = stream >> 3, o = (stream & 7) >> 1;
        id = question[(b * 4 + o) * 256 + l];
    } else {
        id = article[(stream - 64) * 256 + l];
    }
    xemb[(size_t)gid] = f2bf(emb[(size_t)id * 256 + d]);
}

// all 4 weight tensors in one launch (3 x 49152 + 393216 = 540672 uint4-units)
__global__ void pack_weights(const float* __restrict__ g1whh, const float* __restrict__ g1wih,
                             const float* __restrict__ g2whh, const float* __restrict__ g2wih,
                             unsigned short* __restrict__ wpk1, unsigned short* __restrict__ wih1,
                             unsigned short* __restrict__ wpk2, unsigned short* __restrict__ wih2) {
    int i = blockIdx.x * 256 + threadIdx.x;
    const float* src; unsigned short* dst; int j;
    if (i < 49152)       { src = g1whh; dst = wpk1; j = i; }
    else if (i < 98304)  { src = g1wih; dst = wih1; j = i - 49152; }
    else if (i < 147456) { src = g2whh; dst = wpk2; j = i - 98304; }
    else if (i < 540672) { src = g2wih; dst = wih2; j = i - 147456; }
    else return;
    float4 a = ((const float4*)src)[2 * j];
    float4 b = ((const float4*)src)[2 * j + 1];
    uint4 o;
    o.x = (unsigned int)f2bf(a.x) | ((unsigned int)f2bf(a.y) << 16);
    o.y = (unsigned int)f2bf(a.z) | ((unsigned int)f2bf(a.w) << 16);
    o.z = (unsigned int)f2bf(b.x) | ((unsigned int)f2bf(b.y) << 16);
    o.w = (unsigned int)f2bf(b.z) | ((unsigned int)f2bf(b.w) << 16);
    ((uint4*)dst)[j] = o;
}

// ---------------- MFMA GEMM, both GRU dirs fused; dbuf global_load_lds staging ----------------
// R13: double-buffered LDS tiles -> ONE barrier per k-step; prefetch of tile k+1
// overlaps the 16-MFMA compute of tile k. 32 KB LDS (no occupancy loss).
__global__ __launch_bounds__(256)
void gemm_2dir(const unsigned short* __restrict__ A, const unsigned short* __restrict__ B,
               const float* __restrict__ bias, unsigned short* __restrict__ C0,
               unsigned short* __restrict__ C1, int mbase, int K) {
    __shared__ __align__(16) unsigned short At[2][128][32];
    __shared__ __align__(16) unsigned short Bt[2][128][32];
    int tid = threadIdx.x;
    int m0 = blockIdx.x * 128, n0 = blockIdx.y * 128;
    int l = tid & 63, w = tid >> 6;          // 4 waves
    int wm = (w & 1) * 64, wn = (w >> 1) * 64;
    int lr = l & 15, kq = l >> 4;
    int subrow = l >> 2;
    int swc = (l & 3) ^ (subrow & 3);
    const unsigned short* gA0 = A + (size_t)(m0 + w * 32 + subrow) * K + swc * 8;
    const unsigned short* gA1 = A + (size_t)(m0 + w * 32 + 16 + subrow) * K + swc * 8;
    const unsigned short* gB0 = B + (size_t)(n0 + w * 32 + subrow) * K + swc * 8;
    const unsigned short* gB1 = B + (size_t)(n0 + w * 32 + 16 + subrow) * K + swc * 8;
    unsigned short* lA0[2] = { &At[0][w * 32][0],      &At[1][w * 32][0] };
    unsigned short* lA1[2] = { &At[0][w * 32 + 16][0], &At[1][w * 32 + 16][0] };
    unsigned short* lB0[2] = { &Bt[0][w * 32][0],      &Bt[1][w * 32][0] };
    unsigned short* lB1[2] = { &Bt[0][w * 32 + 16][0], &Bt[1][w * 32 + 16][0] };
    int rchunk = (kq ^ (lr & 3)) * 8;
    floatx4 acc[4][4];
#pragma unroll
    for (int i = 0; i < 4; i++)
#pragma unroll
        for (int j = 0; j < 4; j++) acc[i][j] = (floatx4){0.f, 0.f, 0.f, 0.f};
    // prologue: stage tile 0 into buf 0
    gload_lds16(gA0, lA0[0]);
    gload_lds16(gA1, lA1[0]);
    gload_lds16(gB0, lB0[0]);
    gload_lds16(gB1, lB1[0]);
    __syncthreads();
    int cur = 0;
    for (int k0 = 0; k0 < K; k0 += 32) {
        int nxt = cur ^ 1;
        if (k0 + 32 < K) {                    // prefetch next tile (flies under MFMA)
            gload_lds16(gA0 + k0 + 32, lA0[nxt]);
            gload_lds16(gA1 + k0 + 32, lA1[nxt]);
            gload_lds16(gB0 + k0 + 32, lB0[nxt]);
            gload_lds16(gB1 + k0 + 32, lB1[nxt]);
        }
        short8 af[4], bf[4];
#pragma unroll
        for (int i = 0; i < 4; i++) {
            af[i] = *(const short8*)&At[cur][wm + i * 16 + lr][rchunk];
            bf[i] = *(const short8*)&Bt[cur][wn + i * 16 + lr][rchunk];
        }
#pragma unroll
        for (int i = 0; i < 4; i++)
#pragma unroll
            for (int j = 0; j < 4; j++)
                acc[i][j] = __builtin_amdgcn_mfma_f32_16x16x32_bf16(af[i], bf[j], acc[i][j], 0, 0, 0);
        __syncthreads();   // drains prefetch (had MFMA time to fly) + guards buf reuse
        cur = nxt;
    }
    int quad = l >> 4;
#pragma unroll
    for (int i = 0; i < 4; i++) {
#pragma unroll
        for (int j = 0; j < 4; j++) {
            int n = n0 + wn + j * 16 + lr;
            float bs = bias[n];
            unsigned short* dst = (n < 768) ? C0 : C1;
            int nn = (n < 768) ? n : n - 768;
#pragma unroll
            for (int r = 0; r < 4; r++) {
                int m = mbase + m0 + wm + i * 16 + quad * 4 + r;
                dst[(size_t)m * 768 + nn] = f2bf(acc[i][j][r] + bs);
            }
        }
    }
}

// ---------------- GRU scan: 1 stream/block, whh in VGPRs, in-wave gates ----------------
// R12-proven structure (6x8-deep chains; R11's acc split spilled VGPRs).
__global__ __launch_bounds__(512, 2)
void gru_scan_rreg(const unsigned short* __restrict__ gi_f,
                   const unsigned short* __restrict__ gi_b,
                   const unsigned short* __restrict__ whh_bf,
                   const float* __restrict__ bhh,
                   float* __restrict__ out) {
    int blk = blockIdx.x;
    int d = blk & 1, s = blk >> 1;
    const unsigned short* gi_blk = (d ? gi_b : gi_f) + (size_t)s * LSEQ * H3;
    const unsigned short* wb = whh_bf + (size_t)d * H3 * HID;

    __shared__ __align__(16) unsigned short h_pack[2][256];  // double-buffered h (bf16)

    int tid = threadIdx.x;
    int lane = tid & 63, wave = tid >> 6;
    int lr = lane & 15, kq = lane >> 4;

    short8 bq[6][8];
#pragma unroll
    for (int nt = 0; nt < 6; nt++) {
        int row = (nt >> 1) * 256 + wave * 32 + (nt & 1) * 16 + lr;
        const unsigned short* wp = wb + (size_t)row * HID + kq * 8;
#pragma unroll
        for (int kt = 0; kt < 8; kt++)
            bq[nt][kt] = *(const short8*)(wp + kt * 32);
    }

    int hh0 = wave * 32 + lr, hh1 = hh0 + 16;
    float br0 = bhh[d * H3 + hh0],       br1 = bhh[d * H3 + hh1];
    float bz0 = bhh[d * H3 + 256 + hh0], bz1 = bhh[d * H3 + 256 + hh1];
    float bn0 = bhh[d * H3 + 512 + hh0], bn1 = bhh[d * H3 + 512 + hh1];

    int t0 = d ? (LSEQ - 1) : 0;
    int tstep = d ? -1 : 1;

    if (tid < 128) ((unsigned int*)h_pack[0])[tid] = 0;
    float hold0 = 0.f, hold1 = 0.f;

    unsigned short gr0, gz0, gn0, gr1, gz1, gn1;
    {
        const unsigned short* gp = gi_blk + (size_t)t0 * H3;
        gr0 = gp[hh0]; gz0 = gp[256 + hh0]; gn0 = gp[512 + hh0];
        gr1 = gp[hh1]; gz1 = gp[256 + hh1]; gn1 = gp[512 + hh1];
    }
    __syncthreads();

    int cur = 0, t = t0;
    for (int step = 0; step < LSEQ; ++step) {
        unsigned short nr0 = 0, nz0 = 0, nn0 = 0, nr1 = 0, nz1 = 0, nn1 = 0;
        if (step + 1 < LSEQ) {
            const unsigned short* gp = gi_blk + (size_t)(t + tstep) * H3;
            nr0 = gp[hh0]; nz0 = gp[256 + hh0]; nn0 = gp[512 + hh0];
            nr1 = gp[hh1]; nz1 = gp[256 + hh1]; nn1 = gp[512 + hh1];
        }
        floatx4 acc[6];
#pragma unroll
        for (int nt = 0; nt < 6; nt++) acc[nt] = (floatx4){0.f, 0.f, 0.f, 0.f};
#pragma unroll
        for (int kt = 0; kt < 8; kt++) {
            short8 av = *(const short8*)&h_pack[cur][kt * 32 + kq * 8];  // broadcast
#pragma unroll
            for (int nt = 0; nt < 6; nt++)
                acc[nt] = __builtin_amdgcn_mfma_f32_16x16x32_bf16(av, bq[nt][kt], acc[nt], 0, 0, 0);
        }
        float rg0 = fsig(bf2f(gr0) + acc[0][0] + br0);
        float rg1 = fsig(bf2f(gr1) + acc[1][0] + br1);
        float zg0 = fsig(bf2f(gz0) + acc[2][0] + bz0);
        float zg1 = fsig(bf2f(gz1) + acc[3][0] + bz1);
        float ng0 = ftanh(bf2f(gn0) + rg0 * (acc[4][0] + bn0));
        float ng1 = ftanh(bf2f(gn1) + rg1 * (acc[5][0] + bn1));
        float h0 = (1.f - zg0) * ng0 + zg0 * hold0;
        float h1 = (1.f - zg1) * ng1 + zg1 * hold1;
        hold0 = h0; hold1 = h1;
        int nxt = cur ^ 1;
        if (kq == 0) {
            h_pack[nxt][hh0] = f2bf(h0);
            h_pack[nxt][hh1] = f2bf(h1);
            float* op = out + ((size_t)s * LSEQ + t) * H2 + d * HID;
            op[hh0] = h0;
            op[hh1] = h1;
        }
        gr0 = nr0; gz0 = nz0; gn0 = nn0;
        gr1 = nr1; gz1 = nz1; gn1 = nn1;
        __syncthreads();
        cur = nxt; t += tstep;
    }
}

// ---------------- smat via MFMA split-bf16 (trunc-split), FUSED cw/qw dots ----------------
__global__ __launch_bounds__(256)
void smat_mfma(const float* __restrict__ c, const float* __restrict__ q,
               const float* __restrict__ w1, const float* __restrict__ bvec,
               float* __restrict__ smat) {
    __shared__ __align__(16) unsigned short Ah[128][40];
    __shared__ __align__(16) unsigned short Al[128][40];
    __shared__ __align__(16) unsigned short Bh[128][40];
    __shared__ __align__(16) unsigned short Bl[128][40];
    __shared__ float cwl[128];
    __shared__ float qwl[128];
    const float* w2 = w1 + 1024;
    int b = blockIdx.z;
    int m0 = blockIdx.x * 128, n0 = blockIdx.y * 128;
    int tid = threadIdx.x;
    int l = tid & 63, w = tid >> 6;
    int wm = (w & 1) * 64, wn = (w >> 1) * 64;
    int lr = l & 15, koff = (l >> 4) * 8;
    int srow = tid >> 1, scol = (tid & 1) * 16;
    floatx4 acc[4][4];
#pragma unroll
    for (int i = 0; i < 4; i++)
#pragma unroll
        for (int j = 0; j < 4; j++) acc[i][j] = (floatx4){0.f, 0.f, 0.f, 0.f};
    const float* ap0 = c + (size_t)(b * 256 + m0 + srow) * H2 + scol;
    const float* bp0 = q + (size_t)(b * 256 + n0 + srow) * H2 + scol;
    float pcw = 0.f, pqw = 0.f;
    for (int k0 = 0; k0 < H2; k0 += 32) {
        float av[16], bv[16], wv[16], wc[16], wq[16];
        *(float4*)&av[0]  = *(const float4*)(ap0 + k0);
        *(float4*)&av[4]  = *(const float4*)(ap0 + k0 + 4);
        *(float4*)&av[8]  = *(const float4*)(ap0 + k0 + 8);
        *(float4*)&av[12] = *(const float4*)(ap0 + k0 + 12);
        *(float4*)&bv[0]  = *(const float4*)(bp0 + k0);
        *(float4*)&bv[4]  = *(const float4*)(bp0 + k0 + 4);
        *(float4*)&bv[8]  = *(const float4*)(bp0 + k0 + 8);
        *(float4*)&bv[12] = *(const float4*)(bp0 + k0 + 12);
        *(float4*)&wv[0]  = *(const float4*)(w2 + k0 + scol);
        *(float4*)&wv[4]  = *(const float4*)(w2 + k0 + scol + 4);
        *(float4*)&wv[8]  = *(const float4*)(w2 + k0 + scol + 8);
        *(float4*)&wv[12] = *(const float4*)(w2 + k0 + scol + 12);
        *(float4*)&wc[0]  = *(const float4*)(w1 + k0 + scol);
        *(float4*)&wc[4]  = *(const float4*)(w1 + k0 + scol + 4);
        *(float4*)&wc[8]  = *(const float4*)(w1 + k0 + scol + 8);
        *(float4*)&wc[12] = *(const float4*)(w1 + k0 + scol + 12);
        *(float4*)&wq[0]  = *(const float4*)(w1 + 512 + k0 + scol);
        *(float4*)&wq[4]  = *(const float4*)(w1 + 512 + k0 + scol + 4);
        *(float4*)&wq[8]  = *(const float4*)(w1 + 512 + k0 + scol + 8);
        *(float4*)&wq[12] = *(const float4*)(w1 + 512 + k0 + scol + 12);
#pragma unroll
        for (int j = 0; j < 16; j++) { pcw += av[j] * wc[j]; pqw += bv[j] * wq[j]; }
        unsigned int ahw[8], alw[8], bhw[8], blw[8];
#pragma unroll
        for (int j = 0; j < 8; j++) {
            float a0 = av[2 * j] * wv[2 * j], a1 = av[2 * j + 1] * wv[2 * j + 1];
            unsigned int u0 = __float_as_uint(a0), u1 = __float_as_uint(a1);
            ahw[j] = (u0 >> 16) | (u1 & 0xFFFF0000u);
            float r0 = a0 - __uint_as_float(u0 & 0xFFFF0000u);
            float r1 = a1 - __uint_as_float(u1 & 0xFFFF0000u);
            alw[j] = (unsigned int)f2bf(r0) | ((unsigned int)f2bf(r1) << 16);
            unsigned int v0 = __float_as_uint(bv[2 * j]), v1 = __float_as_uint(bv[2 * j + 1]);
            bhw[j] = (v0 >> 16) | (v1 & 0xFFFF0000u);
            float s0 = bv[2 * j]     - __uint_as_float(v0 & 0xFFFF0000u);
            float s1 = bv[2 * j + 1] - __uint_as_float(v1 & 0xFFFF0000u);
            blw[j] = (unsigned int)f2bf(s0) | ((unsigned int)f2bf(s1) << 16);
        }
        __syncthreads();
        *(uint4*)&Ah[srow][scol]     = *(uint4*)&ahw[0];
        *(uint4*)&Ah[srow][scol + 8] = *(uint4*)&ahw[4];
        *(uint4*)&Al[srow][scol]     = *(uint4*)&alw[0];
        *(uint4*)&Al[srow][scol + 8] = *(uint4*)&alw[4];
        *(uint4*)&Bh[srow][scol]     = *(uint4*)&bhw[0];
        *(uint4*)&Bh[srow][scol + 8] = *(uint4*)&bhw[4];
        *(uint4*)&Bl[srow][scol]     = *(uint4*)&blw[0];
        *(uint4*)&Bl[srow][scol + 8] = *(uint4*)&blw[4];
        __syncthreads();
        short8 afh[4], afl[4], bfh[4], bfl[4];
#pragma unroll
        for (int i = 0; i < 4; i++) {
            afh[i] = *(const short8*)&Ah[wm + i * 16 + lr][koff];
            afl[i] = *(const short8*)&Al[wm + i * 16 + lr][koff];
            bfh[i] = *(const short8*)&Bh[wn + i * 16 + lr][koff];
            bfl[i] = *(const short8*)&Bl[wn + i * 16 + lr][koff];
        }
#pragma unroll
        for (int i = 0; i < 4; i++)
#pragma unroll
            for (int j = 0; j < 4; j++) {
                acc[i][j] = __builtin_amdgcn_mfma_f32_16x16x32_bf16(afl[i], bfh[j], acc[i][j], 0, 0, 0);
                acc[i][j] = __builtin_amdgcn_mfma_f32_16x16x32_bf16(afh[i], bfl[j], acc[i][j], 0, 0, 0);
                acc[i][j] = __builtin_amdgcn_mfma_f32_16x16x32_bf16(afh[i], bfh[j], acc[i][j], 0, 0, 0);
            }
    }
    // pair-reduce the cw/qw partial dots (lanes tid, tid^1 share srow)
    pcw += __shfl_xor(pcw, 1);
    pqw += __shfl_xor(pqw, 1);
    if ((tid & 1) == 0) { cwl[srow] = pcw; qwl[srow] = pqw; }
    __syncthreads();
    float bsum = bvec[0] + bvec[1] + bvec[2];
    int quad = l >> 4;
#pragma unroll
    for (int i = 0; i < 4; i++) {
#pragma unroll
        for (int j = 0; j < 4; j++) {
            int n = n0 + wn + j * 16 + lr;
            float qwv = qwl[wn + j * 16 + lr] + bsum;
#pragma unroll
            for (int r = 0; r < 4; r++) {
                int m = m0 + wm + i * 16 + quad * 4 + r;
                smat[((size_t)(b * 256 + m)) * 256 + n] =
                    acc[i][j][r] + cwl[wm + i * 16 + quad * 4 + r] + qwv;
            }
        }
    }
}

__global__ void softmax_kernel(float* __restrict__ smat, float* __restrict__ rowmax) {
    int row = blockIdx.x;
    int lane = threadIdx.x;
    float* p = smat + (size_t)row * LSEQ;
    float v[4];
    float mx = -1e30f;
#pragma unroll
    for (int j = 0; j < 4; j++) { v[j] = p[lane + j * 64]; mx = fmaxf(mx, v[j]); }
    for (int off = 32; off; off >>= 1) mx = fmaxf(mx, __shfl_down(mx, off));
    mx = __shfl(mx, 0);
    float sum = 0.f;
#pragma unroll
    for (int j = 0; j < 4; j++) { v[j] = __expf(v[j] - mx); sum += v[j]; }
    for (int off = 32; off; off >>= 1) sum += __shfl_down(sum, off);
    sum = __shfl(sum, 0);
    float inv = 1.f / sum;
#pragma unroll
    for (int j = 0; j < 4; j++) p[lane + j * 64] = v[j] * inv;
    if (lane == 0) rowmax[row] = mx;
}

__global__ void bb_kernel(const float* __restrict__ rowmax, float* __restrict__ bb) {
    int b = blockIdx.x; int t = threadIdx.x;
    __shared__ float red[256];
    float v = rowmax[b * LSEQ + t];
    red[t] = v; __syncthreads();
    for (int s = 128; s; s >>= 1) { if (t < s) red[t] = fmaxf(red[t], red[t + s]); __syncthreads(); }
    float mx = red[0]; __syncthreads();
    float e = __expf(v - mx);
    red[t] = e; __syncthreads();
    for (int s = 128; s; s >>= 1) { if (t < s) red[t] += red[t + s]; __syncthreads(); }
    bb[b * LSEQ + t] = e / red[0];
}

// q2c: grid (64,4) x 128 thr; 4 independent accumulators break the add chain
__global__ void q2c_kernel(const float* __restrict__ bb, const float* __restrict__ c,
                           float* __restrict__ q2c) {
    int b = blockIdx.x;
    int d = blockIdx.y * 128 + threadIdx.x;
    const float* cb = c + (size_t)b * LSEQ * H2 + d;
    const float* bbp = bb + b * LSEQ;
    float a0 = 0.f, a1 = 0.f, a2 = 0.f, a3 = 0.f;
    for (int i = 0; i < LSEQ; i += 4) {
        a0 += bbp[i]     * cb[(size_t)i * H2];
        a1 += bbp[i + 1] * cb[(size_t)(i + 1) * H2];
        a2 += bbp[i + 2] * cb[(size_t)(i + 2) * H2];
        a3 += bbp[i + 3] * cb[(size_t)(i + 3) * H2];
    }
    q2c[b * H2 + d] = (a0 + a1) + (a2 + a3);
}

// c2q via MFMA split-bf16 (trunc-split) with FUSED fixup03 epilogue; ATT bf16.
__global__ __launch_bounds__(256)
void c2q_fix_mfma(const float* __restrict__ amat, const float* __restrict__ q,
                  const float* __restrict__ c, const float* __restrict__ q2c,
                  unsigned short* __restrict__ att, int add) {
    __shared__ __align__(16) unsigned short Ah[128][40];
    __shared__ __align__(16) unsigned short Al[128][40];
    __shared__ __align__(16) unsigned short Bh[128][40];
    __shared__ __align__(16) unsigned short Bl[128][40];
    int b = blockIdx.z;
    int m0 = blockIdx.x * 128, n0 = blockIdx.y * 128;
    int tid = threadIdx.x;
    int l = tid & 63, w = tid >> 6;
    int wm = (w & 1) * 64, wn = (w >> 1) * 64;
    int lr = l & 15, koff = (l >> 4) * 8;
    int srow = tid >> 1, scol = (tid & 1) * 16;
    int bn = tid & 127, bkh = tid >> 7;           // B-stage: column n0+bn, k-half bkh
    floatx4 acc[4][4];
#pragma unroll
    for (int i = 0; i < 4; i++)
#pragma unroll
        for (int j = 0; j < 4; j++) acc[i][j] = (floatx4){0.f, 0.f, 0.f, 0.f};
    for (int k0 = 0; k0 < LSEQ; k0 += 32) {
        float av[16];
        const float* ap = amat + (size_t)(b * 256 + m0 + srow) * 256 + k0 + scol;
        *(float4*)&av[0]  = *(const float4*)(ap);
        *(float4*)&av[4]  = *(const float4*)(ap + 4);
        *(float4*)&av[8]  = *(const float4*)(ap + 8);
        *(float4*)&av[12] = *(const float4*)(ap + 12);
        float qv[16];
        const float* qp = q + (size_t)(b * 256 + k0 + bkh * 16) * H2 + n0 + bn;
#pragma unroll
        for (int j = 0; j < 16; j++) qv[j] = qp[(size_t)j * H2];
        unsigned int ahw[8], alw[8], bhw[8], blw[8];
#pragma unroll
        for (int j = 0; j < 8; j++) {
            unsigned int u0 = __float_as_uint(av[2 * j]), u1 = __float_as_uint(av[2 * j + 1]);
            ahw[j] = (u0 >> 16) | (u1 & 0xFFFF0000u);
            float r0 = av[2 * j]     - __uint_as_float(u0 & 0xFFFF0000u);
            float r1 = av[2 * j + 1] - __uint_as_float(u1 & 0xFFFF0000u);
            alw[j] = (unsigned int)f2bf(r0) | ((unsigned int)f2bf(r1) << 16);
            unsigned int v0 = __float_as_uint(qv[2 * j]), v1 = __float_as_uint(qv[2 * j + 1]);
            bhw[j] = (v0 >> 16) | (v1 & 0xFFFF0000u);
            float s0 = qv[2 * j]     - __uint_as_float(v0 & 0xFFFF0000u);
            float s1 = qv[2 * j + 1] - __uint_as_float(v1 & 0xFFFF0000u);
            blw[j] = (unsigned int)f2bf(s0) | ((unsigned int)f2bf(s1) << 16);
        }
        __syncthreads();
        *(uint4*)&Ah[srow][scol]         = *(uint4*)&ahw[0];
        *(uint4*)&Ah[srow][scol + 8]     = *(uint4*)&ahw[4];
        *(uint4*)&Al[srow][scol]         = *(uint4*)&alw[0];
        *(uint4*)&Al[srow][scol + 8]     = *(uint4*)&alw[4];
        *(uint4*)&Bh[bn][bkh * 16]       = *(uint4*)&bhw[0];
        *(uint4*)&Bh[bn][bkh * 16 + 8]   = *(uint4*)&bhw[4];
        *(uint4*)&Bl[bn][bkh * 16]       = *(uint4*)&blw[0];
        *(uint4*)&Bl[bn][bkh * 16 + 8]   = *(uint4*)&blw[4];
        __syncthreads();
        short8 afh[4], afl[4], bfh[4], bfl[4];
#pragma unroll
        for (int i = 0; i < 4; i++) {
            afh[i] = *(const short8*)&Ah[wm + i * 16 + lr][koff];
            afl[i] = *(const short8*)&Al[wm + i * 16 + lr][koff];
            bfh[i] = *(const short8*)&Bh[wn + i * 16 + lr][koff];
            bfl[i] = *(const short8*)&Bl[wn + i * 16 + lr][koff];
        }
#pragma unroll
        for (int i = 0; i < 4; i++)
#pragma unroll
            for (int j = 0; j < 4; j++) {
                acc[i][j] = __builtin_amdgcn_mfma_f32_16x16x32_bf16(afl[i], bfh[j], acc[i][j], 0, 0, 0);
                acc[i][j] = __builtin_amdgcn_mfma_f32_16x16x32_bf16(afh[i], bfl[j], acc[i][j], 0, 0, 0);
                acc[i][j] = __builtin_amdgcn_mfma_f32_16x16x32_bf16(afh[i], bfh[j], acc[i][j], 0, 0, 0);
            }
    }
    int quad = l >> 4;
#pragma unroll
    for (int i = 0; i < 4; i++) {
#pragma unroll
        for (int j = 0; j < 4; j++) {
            int n = n0 + wn + j * 16 + lr;
            float q2cv = q2c[b * H2 + n];
#pragma unroll
            for (int r = 0; r < 4; r++) {
                int m = m0 + wm + i * 16 + quad * 4 + r;
                size_t row = (size_t)b * 256 + m;
                float a = acc[i][j][r];
                float cv = c[row * H2 + n];
                float v0 = fmaxf(cv, 0.f);
                float v1 = fmaxf(a, 0.f);
                float v2 = fmaxf(cv * a, 0.f);
                float v3 = fmaxf(cv * q2cv, 0.f);
                unsigned short* p0 = att + row * H8 + n;
                if (add) {
                    p0[0]    = f2bf(bf2f(p0[0])    + v0);
                    p0[512]  = f2bf(bf2f(p0[512])  + v1);
                    p0[1024] = f2bf(bf2f(p0[1024]) + v2);
                    p0[1536] = f2bf(bf2f(p0[1536]) + v3);
                } else {
                    p0[0] = f2bf(v0); p0[512] = f2bf(v1);
                    p0[1024] = f2bf(v2); p0[1536] = f2bf(v3);
                }
            }
        }
    }
}

// ---------------- final rank reduce (bf16 s) ----------------
__global__ void reduce1_kernel(const unsigned short* __restrict__ s, const float* __restrict__ rw,
                               float* __restrict__ part) {
    int bo = blockIdx.x;
    int p = blockIdx.y;
    int t = threadIdx.x;
    const unsigned int* s0 = (const unsigned int*)(s + (size_t)(2 * bo) * 524288 + (size_t)p * 65536);
    const unsigned int* s1 = (const unsigned int*)(s + (size_t)(2 * bo) * 524288 + 524288 + (size_t)p * 65536);
    const float* rwp = rw + (size_t)p * 65536;
    float acc = 0.f;
    for (int j = t; j < 32768; j += 256) {
        unsigned int a = s0[j], b = s1[j];
        float2 rv = *(const float2*)(rwp + 2 * j);
        float x0 = fmaxf(__uint_as_float(a << 16), __uint_as_float(b << 16));
        float x1 = fmaxf(__uint_as_float(a & 0xFFFF0000u), __uint_as_float(b & 0xFFFF0000u));
        acc += rv.x * x0 + rv.y * x1;
    }
    __shared__ float red[256];
    red[t] = acc; __syncthreads();
    for (int ss = 128; ss; ss >>= 1) { if (t < ss) red[t] += red[t + ss]; __syncthreads(); }
    if (t == 0) part[bo * 8 + p] = red[0];
}

__global__ void reduce2_kernel(const float* __restrict__ part, const float* __restrict__ rb,
                               float* __restrict__ out) {
    int t = threadIdx.x;
    float a = rb[0];
    for (int p = 0; p < 8; p++) a += part[t * 8 + p];
    out[t] = a;
}

extern "C" void kernel_launch(void* const* d_in, const int* in_sizes, int n_in,
                              void* d_out, int out_size, void* d_ws, size_t ws_size,
                              hipStream_t stream) {
    const int* question = (const int*)d_in[0];
    const int* article  = (const int*)d_in[1];
    const float* emb    = (const float*)d_in[2];
    const float* g1_wih = (const float*)d_in[3];
    const float* g1_whh = (const float*)d_in[4];
    const float* g1_bih = (const float*)d_in[5];
    const float* g1_bhh = (const float*)d_in[6];
    const float* g2_wih = (const float*)d_in[7];
    const float* g2_whh = (const float*)d_in[8];
    const float* g2_bih = (const float*)d_in[9];
    const float* g2_bhh = (const float*)d_in[10];
    const float* b1_w   = (const float*)d_in[11];
    const float* b1_b   = (const float*)d_in[12];
    const float* b2_w   = (const float*)d_in[13];
    const float* b2_b   = (const float*)d_in[14];
    const float* rank_w = (const float*)d_in[15];
    const float* rank_b = (const float*)d_in[16];
    float* ws = (float*)d_ws;
    float* out = (float*)d_out;

    // ---- workspace layout (float offsets; phase-liveness verified) ----
    unsigned short* WPK1  = (unsigned short*)(ws);
    unsigned short* WIH1B = (unsigned short*)(ws + 196608);
    unsigned short* WPK2  = (unsigned short*)(ws + 393216);
    unsigned short* WIH2B = (unsigned short*)(ws + 589824);
    float* RM   = ws + 2195456;
    float* BBv  = ws + 2211840;
    float* Q2C  = ws + 2228224;
    float* PART = ws + 2260992;
    unsigned short* XEMBB = (unsigned short*)(ws + 2293760);
    float*          SMAT  = ws + 2293760;
    unsigned short* GI2B  = (unsigned short*)(ws + 2293760);
    float*          HBUF  = ws + 6488064;
    float*          AX2   = ws + 14876672;
    unsigned short* ATTB  = (unsigned short*)(ws + 25165824);
    unsigned short* GI1B  = (unsigned short*)(ws + 25165824);

    // 1. embed (bf16) + pack all weights to bf16 (single launch)
    embed_kernel<<<32768, 256, 0, stream>>>(question, article, emb, XEMBB);
    pack_weights<<<2112, 256, 0, stream>>>(g1_whh, g1_wih, g2_whh, g2_wih,
                                           WPK1, WIH1B, WPK2, WIH2B);

    // 2. GRU1 input gates, both dirs fused: M=32768 N=1536 K=256
    gemm_2dir<<<dim3(256, 12), 256, 0, stream>>>(
        XEMBB, WIH1B, g1_bih, GI1B, GI1B + (size_t)25165824, 0, 256);
    // 3. GRU1 scan
    gru_scan_rreg<<<256, 512, 0, stream>>>(GI1B, GI1B + (size_t)25165824, WPK1, g1_bhh, HBUF);

    float* QH = HBUF;
    float* AH = HBUF + (size_t)64 * 256 * 512;

    // 4. BiDAF1: c=QH, q=AH -> ATTB bf16 (set)
    {
        smat_mfma<<<dim3(2, 2, 64), 256, 0, stream>>>(QH, AH, b1_w, b1_b, SMAT);
        softmax_kernel<<<16384, 64, 0, stream>>>(SMAT, RM);
        bb_kernel<<<64, 256, 0, stream>>>(RM, BBv);
        q2c_kernel<<<dim3(64, 4), 128, 0, stream>>>(BBv, QH, Q2C);
        c2q_fix_mfma<<<dim3(2, 4, 64), 256, 0, stream>>>(SMAT, AH, QH, Q2C, ATTB, 0);
    }

    // 5. GRU2 input gates: reads bf16 ATTB directly, M=16384 N=1536 K=2048
    gemm_2dir<<<dim3(128, 12), 256, 0, stream>>>(
        ATTB, WIH2B, g2_bih, GI2B, GI2B + (size_t)12582912, 0, 2048);
    // 6. GRU2 scan
    gru_scan_rreg<<<128, 512, 0, stream>>>(GI2B, GI2B + (size_t)12582912, WPK2, g2_bhh, AX2);

    // 7. BiDAF2: c=q=AX2 -> ATTB (bf16 accumulate)
    {
        smat_mfma<<<dim3(2, 2, 64), 256, 0, stream>>>(AX2, AX2, b2_w, b2_b, SMAT);
        softmax_kernel<<<16384, 64, 0, stream>>>(SMAT, RM);
        bb_kernel<<<64, 256, 0, stream>>>(RM, BBv);
        q2c_kernel<<<dim3(64, 4), 128, 0, stream>>>(BBv, AX2, Q2C);
        c2q_fix_mfma<<<dim3(2, 4, 64), 256, 0, stream>>>(SMAT, AX2, AX2, Q2C, ATTB, 1);
    }

    // 8. rank reduce (bf16 s)
    reduce1_kernel<<<dim3(32, 8), 256, 0, stream>>>(ATTB, rank_w, PART);
    reduce2_kernel<<<1, 32, 0, stream>>>(PART, rank_b, out);
}